// Round 1
// baseline (5231.258 us; speedup 1.0000x reference)
//
#include <hip/hip_runtime.h>
#include <math.h>

#define DIM   64
#define MDIM  32
#define NLAY  16
#define PAD   1
#define NB    2
#define LL    96
#define NN    23
#define NNODE (NB*LL*NN)   /* 4416 */
#define EIN   129
#define EH    258          /* EIN*2 */
#define NH    128          /* DIM*2 */

__device__ __forceinline__ float silu_f(float x) {
    return x / (1.0f + __expf(-x));
}

// ---------------------------------------------------------------------------
// Init: token+pos embedding (canonical layout), copy coords.
// pos logic: within a (b,l) row, token t is constant; if t!=PAD, pos=n+2,
// else pos=PAD and pos_emb[PAD]==0 -> skip the add.
// ---------------------------------------------------------------------------
__global__ void k_embed(const int* __restrict__ tokens,
                        const float* __restrict__ cords,
                        const float* __restrict__ tok_emb,
                        const float* __restrict__ pos_emb,
                        float* __restrict__ feats,
                        float* __restrict__ coors) {
    int idx = blockIdx.x * blockDim.x + threadIdx.x;
    if (idx < NNODE * DIM) {
        int node = idx / DIM, d = idx % DIM;
        int b = node / (LL * NN);
        int rem = node % (LL * NN);
        int n = rem % NN;
        int l = rem / NN;
        int t = tokens[b * LL + l];
        float f = tok_emb[t * DIM + d];
        if (t != PAD) f += pos_emb[(n + 2) * DIM + d];
        feats[idx] = f;
    }
    if (idx < NNODE * 3) coors[idx] = cords[idx];
}

// ---------------------------------------------------------------------------
// Transpose cw1 (NLAY,32,128) -> cw1T (NLAY,128,32) so stage-3 reads are
// contiguous per output unit.
// ---------------------------------------------------------------------------
__global__ void k_tr_cw1(const float* __restrict__ cw1, float* __restrict__ cw1T) {
    int idx = blockIdx.x * blockDim.x + threadIdx.x;
    if (idx >= NLAY * NH * MDIM) return;
    int l = idx / (NH * MDIM);
    int r = idx % (NH * MDIM);
    int o = r / MDIM;
    int k = r % MDIM;
    cw1T[idx] = cw1[l * MDIM * NH + k * NH + o];
}

// ---------------------------------------------------------------------------
// Per-layer node precompute:
//   a[gnode][k] = eb1[k] + f_node @ ew1[0:64, k]
//   bT[k][gnode] =        f_node @ ew1[64:128, k]   (transposed for coalescing)
//   coorsO[gnode] = coors[node]  (orientation order)
// gnode is in the current layer's group-major order.
// ---------------------------------------------------------------------------
__global__ __launch_bounds__(256)
void k_pre(const float* __restrict__ feats, const float* __restrict__ coors,
           const float* __restrict__ ew1L, const float* __restrict__ eb1L,
           float* __restrict__ aBuf, float* __restrict__ bTBuf,
           float* __restrict__ coorsO, int alongL) {
    __shared__ float fl[DIM];
    int gnode = blockIdx.x;
    int nf;
    if (alongL) {
        int g = gnode / LL, j = gnode % LL;   // g = b*NN + n, j = l
        int b = g / NN, n = g % NN;
        nf = (b * LL + j) * NN + n;
    } else {
        nf = gnode;
    }
    int t = threadIdx.x;
    if (t < DIM) fl[t] = feats[nf * DIM + t];
    __syncthreads();
    for (int k = t; k < EH; k += 256) {
        float av = eb1L[k];
        float bv = 0.0f;
#pragma unroll
        for (int d = 0; d < DIM; d++) {
            float f = fl[d];
            av += f * ew1L[d * EH + k];
            bv += f * ew1L[(DIM + d) * EH + k];
        }
        aBuf[gnode * EH + k] = av;
        bTBuf[k * NNODE + gnode] = bv;
    }
    if (t < 3) coorsO[gnode * 3 + t] = coors[nf * 3 + t];
}

// ---------------------------------------------------------------------------
// Fused edge kernel. One thread = one edge (i,j) within a group.
// Block covers TI full i-rows (all j), so m_i and delta are completed
// in-block (LDS reduction), no cross-block accumulation.
// ---------------------------------------------------------------------------
__global__ __launch_bounds__(192)
void k_edge(const float* __restrict__ aBuf, const float* __restrict__ bTBuf,
            const float* __restrict__ coorsO,
            const float* __restrict__ ew1L,   // wd row = ew1L + 128*EH
            const float* __restrict__ ew2L, const float* __restrict__ eb2L,
            const float* __restrict__ cw1TL, const float* __restrict__ cb1L,
            const float* __restrict__ cw2L, const float* __restrict__ cb2L,
            const float* __restrict__ lnbL,
            float* __restrict__ miBuf, float* __restrict__ deltaBuf,
            int Nn, int TI, int bpg) {
    __shared__ float aS[8 * EH];     // max TI = 8
    __shared__ float miS[8 * MDIM];
    __shared__ float dS[8 * 3];

    int g  = blockIdx.x / bpg;
    int rt = blockIdx.x % bpg;
    int i0 = rt * TI;
    int t  = threadIdx.x;
    int nrows = Nn - i0; if (nrows > TI) nrows = TI;

    // stage a rows for this block's i-rows
    for (int x = t; x < nrows * EH; x += 192) {
        int r = x / EH, k = x % EH;
        aS[r * EH + k] = aBuf[(g * Nn + i0 + r) * EH + k];
    }
    for (int x = t; x < 8 * MDIM; x += 192) miS[x] = 0.0f;
    for (int x = t; x < 8 * 3; x += 192) dS[x] = 0.0f;
    __syncthreads();

    int ii = t / Nn, jj = t % Nn;
    bool active = (ii < TI) && (i0 + ii < Nn);
    if (active) {
        int i  = i0 + ii;
        int gi = g * Nn + i;
        int gj = g * Nn + jj;
        float cix = coorsO[gi * 3 + 0], ciy = coorsO[gi * 3 + 1], ciz = coorsO[gi * 3 + 2];
        float cjx = coorsO[gj * 3 + 0], cjy = coorsO[gj * 3 + 1], cjz = coorsO[gj * 3 + 2];
        float rx = cix - cjx, ry = ciy - cjy, rz = ciz - cjz;
        float dist = rx * rx + ry * ry + rz * rz;

        const float* wd   = ew1L + 128 * EH;
        const float* arow = aS + ii * EH;
        const float* bcol = bTBuf + gj;

        float macc[MDIM];
#pragma unroll
        for (int o = 0; o < MDIM; o++) macc[o] = eb2L[o];

        for (int k = 0; k < EH; k++) {
            float h = silu_f(arow[k] + bcol[k * NNODE] + dist * wd[k]);
#pragma unroll
            for (int o = 0; o < MDIM; o++) macc[o] += h * ew2L[k * MDIM + o];
        }
#pragma unroll
        for (int o = 0; o < MDIM; o++) {
            macc[o] = silu_f(macc[o]);                 // m_ij
            atomicAdd(&miS[ii * MDIM + o], macc[o]);   // m_i accumulation
        }

        // stage 3+4: w_ij = silu(m @ cw1 + cb1) @ cw2 + cb2
        float w = cb2L[0];
        for (int o = 0; o < NH; o++) {
            float s = cb1L[o];
#pragma unroll
            for (int k = 0; k < MDIM; k++) s += macc[k] * cw1TL[o * MDIM + k];
            w += silu_f(s) * cw2L[o];
        }

        float beta = lnbL[0];
        float nrm = sqrtf(dist);
        float scale = (w * 0.02f) * beta / fmaxf(nrm, 1e-8f);
        atomicAdd(&dS[ii * 3 + 0], scale * rx);
        atomicAdd(&dS[ii * 3 + 1], scale * ry);
        atomicAdd(&dS[ii * 3 + 2], scale * rz);
    }
    __syncthreads();

    for (int x = t; x < nrows * MDIM; x += 192) {
        int r = x / MDIM, o = x % MDIM;
        miBuf[(g * Nn + i0 + r) * MDIM + o] = miS[r * MDIM + o];
    }
    for (int x = t; x < nrows * 3; x += 192) {
        int r = x / 3, c = x % 3;
        deltaBuf[(g * Nn + i0 + r) * 3 + c] = dS[r * 3 + c];
    }
}

// ---------------------------------------------------------------------------
// Node update: f_out = silu([f, m_i] @ nw1 + nb1) @ nw2 + nb2 + f
//              c_out = c + delta
// ---------------------------------------------------------------------------
__global__ __launch_bounds__(128)
void k_node(const float* __restrict__ featsIn, const float* __restrict__ coorsIn,
            const float* __restrict__ miBuf, const float* __restrict__ deltaBuf,
            const float* __restrict__ nw1L, const float* __restrict__ nb1L,
            const float* __restrict__ nw2L, const float* __restrict__ nb2L,
            float* __restrict__ featsOut, float* __restrict__ coorsOut,
            float* __restrict__ outFinal, int alongL, int isLast) {
    __shared__ float xS[DIM + MDIM];
    __shared__ float hS[NH];
    int nf = blockIdx.x;
    int gnode;
    if (alongL) {
        int b = nf / (LL * NN);
        int rem = nf % (LL * NN);
        int l = rem / NN, n = rem % NN;
        gnode = (b * NN + n) * LL + l;
    } else {
        gnode = nf;
    }
    int t = threadIdx.x;
    if (t < DIM) xS[t] = featsIn[nf * DIM + t];
    else if (t < DIM + MDIM) xS[t] = miBuf[gnode * MDIM + (t - DIM)];
    __syncthreads();

    float s = nb1L[t];
#pragma unroll
    for (int d = 0; d < DIM + MDIM; d++) s += xS[d] * nw1L[d * NH + t];
    hS[t] = silu_f(s);
    __syncthreads();

    if (t < DIM) {
        float o = nb2L[t] + xS[t];
#pragma unroll
        for (int k = 0; k < NH; k++) o += hS[k] * nw2L[k * DIM + t];
        featsOut[nf * DIM + t] = o;
    }
    if (t < 3) {
        float c = coorsIn[nf * 3 + t] + deltaBuf[gnode * 3 + t];
        if (isLast) outFinal[nf * 3 + t] = c;
        else        coorsOut[nf * 3 + t] = c;
    }
}

// ---------------------------------------------------------------------------
extern "C" void kernel_launch(void* const* d_in, const int* in_sizes, int n_in,
                              void* d_out, int out_size, void* d_ws, size_t ws_size,
                              hipStream_t stream) {
    (void)in_sizes; (void)n_in; (void)out_size; (void)ws_size;

    const int*   tokens  = (const int*)d_in[0];
    const float* cords   = (const float*)d_in[1];
    const float* tok_emb = (const float*)d_in[2];
    const float* pos_emb = (const float*)d_in[3];
    const float* ew1 = (const float*)d_in[4];
    const float* eb1 = (const float*)d_in[5];
    const float* ew2 = (const float*)d_in[6];
    const float* eb2 = (const float*)d_in[7];
    const float* cw1 = (const float*)d_in[8];
    const float* cb1 = (const float*)d_in[9];
    const float* cw2 = (const float*)d_in[10];
    const float* cb2 = (const float*)d_in[11];
    const float* nw1 = (const float*)d_in[12];
    const float* nb1 = (const float*)d_in[13];
    const float* nw2 = (const float*)d_in[14];
    const float* nb2 = (const float*)d_in[15];
    /* d_in[16] = ln_g : multiplied by zeros in the reference -> unused */
    const float* lnb = (const float*)d_in[17];

    float* ws = (float*)d_ws;
    float* featsA = ws; ws += NNODE * DIM;
    float* featsB = ws; ws += NNODE * DIM;
    float* coorsA = ws; ws += NNODE * 3;
    float* coorsB = ws; ws += NNODE * 3;
    float* aBuf   = ws; ws += NNODE * EH;
    float* bTBuf  = ws; ws += EH * NNODE;
    float* coorsO = ws; ws += NNODE * 3;
    float* miBuf  = ws; ws += NNODE * MDIM;
    float* deltaB = ws; ws += NNODE * 3;
    float* cw1T   = ws; ws += NLAY * NH * MDIM;

    k_tr_cw1<<<(NLAY * NH * MDIM + 255) / 256, 256, 0, stream>>>(cw1, cw1T);
    k_embed<<<(NNODE * DIM + 255) / 256, 256, 0, stream>>>(
        tokens, cords, tok_emb, pos_emb, featsA, coorsA);

    float* fIn = featsA; float* fOut = featsB;
    float* cIn = coorsA; float* cOut = coorsB;

    for (int L = 0; L < NLAY; L++) {
        int alongL = (L / 4) % 2;              // L0-3:N, L4-7:l, L8-11:N, L12-15:l
        int Nn = alongL ? LL : NN;
        int TI = alongL ? 2 : 8;
        int bpg = (Nn + TI - 1) / TI;
        int groups = NNODE / Nn;

        k_pre<<<NNODE, 256, 0, stream>>>(
            fIn, cIn, ew1 + L * EIN * EH, eb1 + L * EH, aBuf, bTBuf, coorsO, alongL);

        k_edge<<<groups * bpg, 192, 0, stream>>>(
            aBuf, bTBuf, coorsO,
            ew1 + L * EIN * EH, ew2 + L * EH * MDIM, eb2 + L * MDIM,
            cw1T + L * NH * MDIM, cb1 + L * NH, cw2 + L * NH, cb2 + L,
            lnb + L, miBuf, deltaB, Nn, TI, bpg);

        int isLast = (L == NLAY - 1);
        k_node<<<NNODE, 128, 0, stream>>>(
            fIn, cIn, miBuf, deltaB,
            nw1 + L * (DIM + MDIM) * NH, nb1 + L * NH,
            nw2 + L * NH * DIM, nb2 + L * DIM,
            fOut, cOut, (float*)d_out, alongL, isLast);

        float* tmp = fIn; fIn = fOut; fOut = tmp;
        tmp = cIn; cIn = cOut; cOut = tmp;
    }
}

// Round 2
// 3882.389 us; speedup vs baseline: 1.3474x; 1.3474x over previous
//
#include <hip/hip_runtime.h>
#include <math.h>

#define DIM   64
#define MDIM  32
#define NLAY  16
#define PAD   1
#define NB    2
#define LL    96
#define NN    23
#define NNODE (NB*LL*NN)   /* 4416 */
#define EIN   129
#define EH    258          /* EIN*2 */
#define KP    272          /* EH padded to 17*16 for K of mfma 32x32x16 */
#define NK0   17           /* KP/16 */
#define NH    128          /* DIM*2 */

typedef __attribute__((ext_vector_type(8)))  short        bf16x8;
typedef __attribute__((ext_vector_type(16))) float        f32x16;
typedef __attribute__((ext_vector_type(4)))  unsigned int uint4v;

__device__ __forceinline__ float silu_f(float x) {
    return x / (1.0f + __expf(-x));
}
__device__ __forceinline__ unsigned short bf16_rn(float x) {
    unsigned u = __float_as_uint(x);
    u += 0x7FFF + ((u >> 16) & 1);
    return (unsigned short)(u >> 16);
}

// ---------------------------------------------------------------------------
// Embedding init (canonical layout), copy coords.
// ---------------------------------------------------------------------------
__global__ void k_embed(const int* __restrict__ tokens,
                        const float* __restrict__ cords,
                        const float* __restrict__ tok_emb,
                        const float* __restrict__ pos_emb,
                        float* __restrict__ feats,
                        float* __restrict__ coors) {
    int idx = blockIdx.x * blockDim.x + threadIdx.x;
    if (idx < NNODE * DIM) {
        int node = idx / DIM, d = idx % DIM;
        int b = node / (LL * NN);
        int rem = node % (LL * NN);
        int n = rem % NN;
        int l = rem / NN;
        int t = tokens[b * LL + l];
        float f = tok_emb[t * DIM + d];
        if (t != PAD) f += pos_emb[(n + 2) * DIM + d];
        feats[idx] = f;
    }
    if (idx < NNODE * 3) coors[idx] = cords[idx];
}

// ---------------------------------------------------------------------------
// One-time weight prep into MFMA-fragment-friendly bf16 layouts.
//  wdH [L][KP]                : dist row of ew1 (row 128), zero-padded
//  ew2P[L][k0][lane][8]       : B-frag for stage2 (n=lane&31, k=k0*16+(lane>>5)*8+j)
//  cw1P[L][mb][k0][lane][8]   : A-frag for stage3 S^T=cw1^T@m^T
//                               (m=o=mb*32+(lane&31), k=n'=k0*16+(lane>>5)*8+j)
//  cb1P/cw2P[L][half][mb][reg]: f32, reordered to C/D row mapping
// ---------------------------------------------------------------------------
__global__ void k_prep(const float* __restrict__ ew1, const float* __restrict__ ew2,
                       const float* __restrict__ cw1, const float* __restrict__ cb1,
                       const float* __restrict__ cw2,
                       unsigned short* __restrict__ wdH, unsigned short* __restrict__ ew2P,
                       unsigned short* __restrict__ cw1P,
                       float* __restrict__ cb1P, float* __restrict__ cw2P) {
    int idx = blockIdx.x * blockDim.x + threadIdx.x;
    if (idx < NLAY * KP) {
        int L = idx / KP, k = idx % KP;
        float v = (k < EH) ? ew1[(size_t)L * EIN * EH + 128 * EH + k] : 0.0f;
        wdH[idx] = bf16_rn(v);
    }
    if (idx < NLAY * NK0 * 512) {
        int L = idx / (NK0 * 512); int r = idx % (NK0 * 512);
        int k0 = r / 512; int r2 = r % 512;
        int lane = r2 >> 3, j = r2 & 7;
        int k = k0 * 16 + (lane >> 5) * 8 + j;
        int n = lane & 31;
        float v = (k < EH) ? ew2[((size_t)L * EH + k) * MDIM + n] : 0.0f;
        ew2P[idx] = bf16_rn(v);
    }
    if (idx < NLAY * 4096) {
        int L = idx / 4096; int r = idx % 4096;
        int mb = r / 1024; int r2 = r % 1024;
        int k0 = r2 / 512; int r3 = r2 % 512;
        int lane = r3 >> 3, j = r3 & 7;
        int k = k0 * 16 + (lane >> 5) * 8 + j;   // n' in [0,32)
        int o = mb * 32 + (lane & 31);
        cw1P[idx] = bf16_rn(cw1[((size_t)L * MDIM + k) * NH + o]);
    }
    if (idx < NLAY * 128) {
        int L = idx / 128; int r = idx % 128;
        int hlf = r / 64; int r2 = r % 64;
        int mb = r2 / 16, reg = r2 % 16;
        int o = mb * 32 + (reg & 3) + 8 * (reg >> 2) + 4 * hlf;
        cb1P[idx] = cb1[L * NH + o];
        cw2P[idx] = cw2[L * NH + o];
    }
}

// ---------------------------------------------------------------------------
// Per-layer node precompute (bf16 output, padded K):
//   aH[gnode][k] = bf16(eb1[k] + f @ ew1[0:64,k]),  bH[gnode][k] = bf16(f @ ew1[64:128,k])
// ---------------------------------------------------------------------------
__global__ __launch_bounds__(256)
void k_pre(const float* __restrict__ feats, const float* __restrict__ coors,
           const float* __restrict__ ew1L, const float* __restrict__ eb1L,
           unsigned short* __restrict__ aH, unsigned short* __restrict__ bH,
           float* __restrict__ coorsO, int alongL) {
    __shared__ float fl[DIM];
    int gnode = blockIdx.x;
    int nf;
    if (alongL) {
        int g = gnode / LL, j = gnode % LL;   // g = b*NN + n, j = l
        int b = g / NN, n = g % NN;
        nf = (b * LL + j) * NN + n;
    } else {
        nf = gnode;
    }
    int t = threadIdx.x;
    if (t < DIM) fl[t] = feats[nf * DIM + t];
    __syncthreads();
    for (int k = t; k < KP; k += 256) {
        if (k < EH) {
            float av = eb1L[k];
            float bv = 0.0f;
#pragma unroll
            for (int d = 0; d < DIM; d++) {
                float f = fl[d];
                av += f * ew1L[d * EH + k];
                bv += f * ew1L[(DIM + d) * EH + k];
            }
            aH[(size_t)gnode * KP + k] = bf16_rn(av);
            bH[(size_t)gnode * KP + k] = bf16_rn(bv);
        } else {
            aH[(size_t)gnode * KP + k] = 0;
            bH[(size_t)gnode * KP + k] = 0;
        }
    }
    if (t < 3) coorsO[gnode * 3 + t] = coors[nf * 3 + t];
}

// ---------------------------------------------------------------------------
// MFMA edge kernel. One wave = one i-row of one group; loops over 32-j tiles.
// Stage2: C[j][n] = H(32j x KP) @ ew2(KP x 32)      (17 mfma_32x32x16_bf16)
// Stage3: S^T[o][j] = cw1^T(128x32) @ m^T(32 x 32j) (8 mfma, via LDS transpose)
// Stage4: w[j] = cb2 + sum_o silu(S+cb1)*cw2 ; delta_i += w*(0.02*beta/|r|)*r
// ---------------------------------------------------------------------------
__global__ __launch_bounds__(256)
void k_edge(const unsigned short* __restrict__ aH,
            const unsigned short* __restrict__ bH,
            const float* __restrict__ coorsO,
            const unsigned short* __restrict__ wdHL,
            const unsigned short* __restrict__ ew2PL,
            const float* __restrict__ eb2L,
            const unsigned short* __restrict__ cw1PL,
            const float* __restrict__ cb1PL,
            const float* __restrict__ cw2PL,
            const float* __restrict__ cb2L,
            const float* __restrict__ lnbL,
            float* __restrict__ miBuf, float* __restrict__ deltaBuf,
            int Nn, int njt) {
    __shared__ unsigned short mT[4][32 * 36];   // [n'][edge], pitch 36 (conflict-free)

    int wave = threadIdx.x >> 6;
    int lane = threadIdx.x & 63;
    int half = lane >> 5;
    int e    = lane & 31;          // A-role: edge (j) ; C-role: col (n / o-local)
    int widx = blockIdx.x * 4 + wave;
    int g = widx / Nn, i = widx % Nn;
    int gi = g * Nn + i;

    float cix = coorsO[gi * 3 + 0], ciy = coorsO[gi * 3 + 1], ciz = coorsO[gi * 3 + 2];
    float eb2v = eb2L[e];
    float beta = lnbL[0];
    float cb2v = cb2L[0];

    const unsigned short* aRow = aH + (size_t)gi * KP;
    unsigned short* mW = &mT[wave][0];

    float miAcc = 0.0f;
    float dAx = 0.0f, dAy = 0.0f, dAz = 0.0f;

    for (int jt = 0; jt < njt; jt++) {
        int j = jt * 32 + e;
        int jc = (j < Nn) ? j : (Nn - 1);
        bool valid = (j < Nn);
        int gj = g * Nn + jc;
        float cjx = coorsO[gj * 3 + 0], cjy = coorsO[gj * 3 + 1], cjz = coorsO[gj * 3 + 2];
        float rx = cix - cjx, ry = ciy - cjy, rz = ciz - cjz;
        float dist = rx * rx + ry * ry + rz * rz;

        const unsigned short* bRow = bH + (size_t)gj * KP;

        // ---- stage 2: 17 MFMAs over padded K ----
        f32x16 acc;
#pragma unroll
        for (int r = 0; r < 16; r++) acc[r] = 0.0f;

        for (int k0 = 0; k0 < NK0; k0++) {
            int ko = k0 * 16 + half * 8;
            uint4v au = *(const uint4v*)(aRow + ko);
            uint4v bu = *(const uint4v*)(bRow + ko);
            uint4v wu = *(const uint4v*)(wdHL + ko);
            uint4v eu = *(const uint4v*)(ew2PL + ((size_t)k0 * 64 + lane) * 8);
            uint4v hu;
#pragma unroll
            for (int p = 0; p < 4; p++) {
                float aL = __uint_as_float(au[p] << 16);
                float aU = __uint_as_float(au[p] & 0xFFFF0000u);
                float bL = __uint_as_float(bu[p] << 16);
                float bU = __uint_as_float(bu[p] & 0xFFFF0000u);
                float wL = __uint_as_float(wu[p] << 16);
                float wU = __uint_as_float(wu[p] & 0xFFFF0000u);
                float hL = silu_f(aL + bL + dist * wL);
                float hU = silu_f(aU + bU + dist * wU);
                hu[p] = (__float_as_uint(hL) >> 16) | (__float_as_uint(hU) & 0xFFFF0000u);
            }
            acc = __builtin_amdgcn_mfma_f32_32x32x16_bf16(
                      __builtin_bit_cast(bf16x8, hu),
                      __builtin_bit_cast(bf16x8, eu), acc, 0, 0, 0);
        }

        // ---- stage 2 epilogue: m_ij = silu(acc + eb2[n]); accumulate m_i; stage m^T ----
        float mv[16];
#pragma unroll
        for (int r = 0; r < 16; r++) {
            int row = (r & 3) + 8 * (r >> 2) + 4 * half;   // edge (j within tile)
            float m = silu_f(acc[r] + eb2v);
            m = (jt * 32 + row < Nn) ? m : 0.0f;
            mv[r] = m;
            miAcc += m;
        }
#pragma unroll
        for (int q = 0; q < 4; q++) {
            unsigned lo = (__float_as_uint(mv[q * 4 + 0]) >> 16) |
                          (__float_as_uint(mv[q * 4 + 1]) & 0xFFFF0000u);
            unsigned hi = (__float_as_uint(mv[q * 4 + 2]) >> 16) |
                          (__float_as_uint(mv[q * 4 + 3]) & 0xFFFF0000u);
            int row0 = 8 * q + 4 * half;
            *(uint2*)&mW[e * 36 + row0] = make_uint2(lo, hi);   // [n=e][edge=row0..+3]
        }

        // ---- stage 3: B-frags (m^T) from LDS ----
        bf16x8 bq[2];
#pragma unroll
        for (int k0 = 0; k0 < 2; k0++) {
            uint4v t;
#pragma unroll
            for (int p = 0; p < 4; p++) {
                unsigned v0 = mW[(k0 * 16 + half * 8 + 2 * p    ) * 36 + e];
                unsigned v1 = mW[(k0 * 16 + half * 8 + 2 * p + 1) * 36 + e];
                t[p] = v0 | (v1 << 16);
            }
            bq[k0] = __builtin_bit_cast(bf16x8, t);
        }

        float wAcc = 0.0f;
#pragma unroll
        for (int mb = 0; mb < 4; mb++) {
            f32x16 s;
#pragma unroll
            for (int r = 0; r < 16; r++) s[r] = 0.0f;
#pragma unroll
            for (int k0 = 0; k0 < 2; k0++) {
                uint4v cu = *(const uint4v*)(cw1PL + ((size_t)(mb * 2 + k0) * 64 + lane) * 8);
                s = __builtin_amdgcn_mfma_f32_32x32x16_bf16(
                        __builtin_bit_cast(bf16x8, cu), bq[k0], s, 0, 0, 0);
            }
            const float* cb1q = cb1PL + (half * 4 + mb) * 16;
            const float* cw2q = cw2PL + (half * 4 + mb) * 16;
#pragma unroll
            for (int r = 0; r < 16; r++) {
                wAcc += silu_f(s[r] + cb1q[r]) * cw2q[r];
            }
        }
        wAcc += __shfl_xor(wAcc, 32, 64);
        float w = wAcc + cb2v;
        float nrm = sqrtf(dist);
        float scale = (w * 0.02f) * beta / fmaxf(nrm, 1e-8f);
        if (valid && half == 0) {
            dAx += scale * rx; dAy += scale * ry; dAz += scale * rz;
        }
    }

    // ---- final reductions ----
    miAcc += __shfl_xor(miAcc, 32, 64);
    if (half == 0) miBuf[gi * MDIM + e] = miAcc;

#pragma unroll
    for (int m = 16; m >= 1; m >>= 1) {
        dAx += __shfl_xor(dAx, m, 64);
        dAy += __shfl_xor(dAy, m, 64);
        dAz += __shfl_xor(dAz, m, 64);
    }
    if (lane == 0) {
        deltaBuf[gi * 3 + 0] = dAx;
        deltaBuf[gi * 3 + 1] = dAy;
        deltaBuf[gi * 3 + 2] = dAz;
    }
}

// ---------------------------------------------------------------------------
// Node update: f_out = silu([f, m_i] @ nw1 + nb1) @ nw2 + nb2 + f ; c += delta
// ---------------------------------------------------------------------------
__global__ __launch_bounds__(128)
void k_node(const float* __restrict__ featsIn, const float* __restrict__ coorsIn,
            const float* __restrict__ miBuf, const float* __restrict__ deltaBuf,
            const float* __restrict__ nw1L, const float* __restrict__ nb1L,
            const float* __restrict__ nw2L, const float* __restrict__ nb2L,
            float* __restrict__ featsOut, float* __restrict__ coorsOut,
            float* __restrict__ outFinal, int alongL, int isLast) {
    __shared__ float xS[DIM + MDIM];
    __shared__ float hS[NH];
    int nf = blockIdx.x;
    int gnode;
    if (alongL) {
        int b = nf / (LL * NN);
        int rem = nf % (LL * NN);
        int l = rem / NN, n = rem % NN;
        gnode = (b * NN + n) * LL + l;
    } else {
        gnode = nf;
    }
    int t = threadIdx.x;
    if (t < DIM) xS[t] = featsIn[nf * DIM + t];
    else if (t < DIM + MDIM) xS[t] = miBuf[gnode * MDIM + (t - DIM)];
    __syncthreads();

    float s = nb1L[t];
#pragma unroll
    for (int d = 0; d < DIM + MDIM; d++) s += xS[d] * nw1L[d * NH + t];
    hS[t] = silu_f(s);
    __syncthreads();

    if (t < DIM) {
        float o = nb2L[t] + xS[t];
#pragma unroll
        for (int k = 0; k < NH; k++) o += hS[k] * nw2L[k * DIM + t];
        featsOut[nf * DIM + t] = o;
    }
    if (t < 3) {
        float c = coorsIn[nf * 3 + t] + deltaBuf[gnode * 3 + t];
        if (isLast) outFinal[nf * 3 + t] = c;
        else        coorsOut[nf * 3 + t] = c;
    }
}

// ---------------------------------------------------------------------------
extern "C" void kernel_launch(void* const* d_in, const int* in_sizes, int n_in,
                              void* d_out, int out_size, void* d_ws, size_t ws_size,
                              hipStream_t stream) {
    (void)in_sizes; (void)n_in; (void)out_size; (void)ws_size;

    const int*   tokens  = (const int*)d_in[0];
    const float* cords   = (const float*)d_in[1];
    const float* tok_emb = (const float*)d_in[2];
    const float* pos_emb = (const float*)d_in[3];
    const float* ew1 = (const float*)d_in[4];
    const float* eb1 = (const float*)d_in[5];
    const float* ew2 = (const float*)d_in[6];
    const float* eb2 = (const float*)d_in[7];
    const float* cw1 = (const float*)d_in[8];
    const float* cb1 = (const float*)d_in[9];
    const float* cw2 = (const float*)d_in[10];
    const float* cb2 = (const float*)d_in[11];
    const float* nw1 = (const float*)d_in[12];
    const float* nb1 = (const float*)d_in[13];
    const float* nw2 = (const float*)d_in[14];
    const float* nb2 = (const float*)d_in[15];
    /* d_in[16] = ln_g : multiplied by zeros in the reference -> unused */
    const float* lnb = (const float*)d_in[17];

    // -------- workspace carve-up (floats first, then bf16/ushort; 16B aligned) ----
    float* wf = (float*)d_ws;
    float* featsA = wf; wf += NNODE * DIM;
    float* featsB = wf; wf += NNODE * DIM;
    float* coorsA = wf; wf += NNODE * 3;     // 13248 (mult of 4)
    float* coorsB = wf; wf += NNODE * 3;
    float* coorsO = wf; wf += NNODE * 3;
    float* miBuf  = wf; wf += NNODE * MDIM;
    float* deltaB = wf; wf += NNODE * 3;
    float* cb1P   = wf; wf += NLAY * 128;
    float* cw2P   = wf; wf += NLAY * 128;

    unsigned short* wh = (unsigned short*)wf;
    unsigned short* aHb  = wh; wh += (size_t)NNODE * KP;
    unsigned short* bHb  = wh; wh += (size_t)NNODE * KP;
    unsigned short* wdH  = wh; wh += NLAY * KP;
    unsigned short* ew2P = wh; wh += NLAY * NK0 * 512;
    unsigned short* cw1P = wh; wh += NLAY * 4096;

    k_prep<<<(NLAY * NK0 * 512 + 255) / 256, 256, 0, stream>>>(
        ew1, ew2, cw1, cb1, cw2, wdH, ew2P, cw1P, cb1P, cw2P);
    k_embed<<<(NNODE * DIM + 255) / 256, 256, 0, stream>>>(
        tokens, cords, tok_emb, pos_emb, featsA, coorsA);

    float* fIn = featsA; float* fOut = featsB;
    float* cIn = coorsA; float* cOut = coorsB;

    for (int L = 0; L < NLAY; L++) {
        int alongL = (L / 4) % 2;              // L0-3:N, L4-7:l, L8-11:N, L12-15:l
        int Nn  = alongL ? LL : NN;
        int njt = alongL ? 3 : 1;

        k_pre<<<NNODE, 256, 0, stream>>>(
            fIn, cIn, ew1 + (size_t)L * EIN * EH, eb1 + L * EH, aHb, bHb, coorsO, alongL);

        k_edge<<<NNODE / 4, 256, 0, stream>>>(
            aHb, bHb, coorsO,
            wdH + L * KP, ew2P + (size_t)L * NK0 * 512, eb2 + L * MDIM,
            cw1P + (size_t)L * 4096, cb1P + L * 128, cw2P + L * 128,
            cb2 + L, lnb + L, miBuf, deltaB, Nn, njt);

        int isLast = (L == NLAY - 1);
        k_node<<<NNODE, 128, 0, stream>>>(
            fIn, cIn, miBuf, deltaB,
            nw1 + (size_t)L * (DIM + MDIM) * NH, nb1 + L * NH,
            nw2 + (size_t)L * NH * DIM, nb2 + L * DIM,
            fOut, cOut, (float*)d_out, alongL, isLast);

        float* tmp = fIn; fIn = fOut; fOut = tmp;
        tmp = cIn; cIn = cOut; cOut = tmp;
    }
}

// Round 3
// 2848.078 us; speedup vs baseline: 1.8368x; 1.3632x over previous
//
#include <hip/hip_runtime.h>
#include <math.h>

#define DIM   64
#define MDIM  32
#define NLAY  16
#define PAD   1
#define NB    2
#define LL    96
#define NN    23
#define NNODE (NB*LL*NN)   /* 4416 */
#define EIN   129
#define EH    258          /* EIN*2 */
#define KP    272          /* EH padded to 17*16 for K of mfma 32x32x16 */
#define NK0   17           /* KP/16 */
#define NH    128          /* DIM*2 */
#define BPITCH 276         /* bS pitch in shorts: 552B, dword-stride 138 = 2-way free */
#define APITCH 274         /* aS pitch in floats: 1096B, 8B aligned */

typedef __attribute__((ext_vector_type(8)))  short        bf16x8;
typedef __attribute__((ext_vector_type(16))) float        f32x16;
typedef __attribute__((ext_vector_type(4)))  unsigned int uint4v;

__device__ __forceinline__ float silu_f(float x) {
    return x / (1.0f + __expf(-x));
}
__device__ __forceinline__ unsigned short bf16_rn(float x) {
    unsigned u = __float_as_uint(x);
    u += 0x7FFF + ((u >> 16) & 1);
    return (unsigned short)(u >> 16);
}
__device__ __forceinline__ float bf16_up(unsigned short h) {
    return __uint_as_float(((unsigned)h) << 16);
}

// ---------------------------------------------------------------------------
// Embedding init (canonical layout), copy coords.
// ---------------------------------------------------------------------------
__global__ void k_embed(const int* __restrict__ tokens,
                        const float* __restrict__ cords,
                        const float* __restrict__ tok_emb,
                        const float* __restrict__ pos_emb,
                        float* __restrict__ feats,
                        float* __restrict__ coors) {
    int idx = blockIdx.x * blockDim.x + threadIdx.x;
    if (idx < NNODE * DIM) {
        int node = idx / DIM, d = idx % DIM;
        int b = node / (LL * NN);
        int rem = node % (LL * NN);
        int n = rem % NN;
        int l = rem / NN;
        int t = tokens[b * LL + l];
        float f = tok_emb[t * DIM + d];
        if (t != PAD) f += pos_emb[(n + 2) * DIM + d];
        feats[idx] = f;
    }
    if (idx < NNODE * 3) coors[idx] = cords[idx];
}

// ---------------------------------------------------------------------------
// One-time weight prep into MFMA-fragment-friendly layouts.
// ---------------------------------------------------------------------------
__global__ void k_prep(const float* __restrict__ ew1, const float* __restrict__ ew2,
                       const float* __restrict__ cw1, const float* __restrict__ cb1,
                       const float* __restrict__ cw2,
                       float* __restrict__ wdF, unsigned short* __restrict__ ew2P,
                       unsigned short* __restrict__ cw1P,
                       float* __restrict__ cb1P, float* __restrict__ cw2P) {
    int idx = blockIdx.x * blockDim.x + threadIdx.x;
    if (idx < NLAY * KP) {
        int L = idx / KP, k = idx % KP;
        float v = (k < EH) ? ew1[(size_t)L * EIN * EH + 128 * EH + k] : 0.0f;
        // store as bf16-rounded f32 so edge kernel matches bf16 precision path
        wdF[idx] = bf16_up(bf16_rn(v));
    }
    if (idx < NLAY * NK0 * 512) {
        int L = idx / (NK0 * 512); int r = idx % (NK0 * 512);
        int k0 = r / 512; int r2 = r % 512;
        int lane = r2 >> 3, j = r2 & 7;
        int k = k0 * 16 + (lane >> 5) * 8 + j;
        int n = lane & 31;
        float v = (k < EH) ? ew2[((size_t)L * EH + k) * MDIM + n] : 0.0f;
        ew2P[idx] = bf16_rn(v);
    }
    if (idx < NLAY * 4096) {
        int L = idx / 4096; int r = idx % 4096;
        int mb = r / 1024; int r2 = r % 1024;
        int k0 = r2 / 512; int r3 = r2 % 512;
        int lane = r3 >> 3, j = r3 & 7;
        int k = k0 * 16 + (lane >> 5) * 8 + j;   // n' in [0,32)
        int o = mb * 32 + (lane & 31);
        cw1P[idx] = bf16_rn(cw1[((size_t)L * MDIM + k) * NH + o]);
    }
    if (idx < NLAY * 128) {
        int L = idx / 128; int r = idx % 128;
        int hlf = r / 64; int r2 = r % 64;
        int mb = r2 / 16, reg = r2 % 16;
        int o = mb * 32 + (reg & 3) + 8 * (reg >> 2) + 4 * hlf;
        cb1P[idx] = cb1[L * NH + o];
        cw2P[idx] = cw2[L * NH + o];
    }
}

// ---------------------------------------------------------------------------
// Per-layer node precompute (bf16, padded K) + zero the atomic accumulators.
// ---------------------------------------------------------------------------
__global__ __launch_bounds__(256)
void k_pre(const float* __restrict__ feats, const float* __restrict__ coors,
           const float* __restrict__ ew1L, const float* __restrict__ eb1L,
           unsigned short* __restrict__ aH, unsigned short* __restrict__ bH,
           float* __restrict__ coorsO, float* __restrict__ miBuf,
           float* __restrict__ deltaBuf, int alongL) {
    __shared__ float fl[DIM];
    int gnode = blockIdx.x;
    int nf;
    if (alongL) {
        int g = gnode / LL, j = gnode % LL;   // g = b*NN + n, j = l
        int b = g / NN, n = g % NN;
        nf = (b * LL + j) * NN + n;
    } else {
        nf = gnode;
    }
    int t = threadIdx.x;
    if (t < DIM) fl[t] = feats[nf * DIM + t];
    __syncthreads();
    for (int k = t; k < KP; k += 256) {
        if (k < EH) {
            float av = eb1L[k];
            float bv = 0.0f;
#pragma unroll
            for (int d = 0; d < DIM; d++) {
                float f = fl[d];
                av += f * ew1L[d * EH + k];
                bv += f * ew1L[(DIM + d) * EH + k];
            }
            aH[(size_t)gnode * KP + k] = bf16_rn(av);
            bH[(size_t)gnode * KP + k] = bf16_rn(bv);
        } else {
            aH[(size_t)gnode * KP + k] = 0;
            bH[(size_t)gnode * KP + k] = 0;
        }
    }
    if (t < MDIM) miBuf[gnode * MDIM + t] = 0.0f;
    if (t < 3) {
        coorsO[gnode * 3 + t] = coors[nf * 3 + t];
        deltaBuf[gnode * 3 + t] = 0.0f;
    }
}

// ---------------------------------------------------------------------------
// MFMA edge kernel v2. Block = (group, 8-i-tile, 32-j-tile).
// All hot data staged in LDS once per block (coalesced). One wave = 2 i-rows.
// m_i / delta accumulated via global f32 atomics (zeroed in k_pre).
// ---------------------------------------------------------------------------
__global__ __launch_bounds__(256, 3)
void k_edge(const unsigned short* __restrict__ aH,
            const unsigned short* __restrict__ bH,
            const float* __restrict__ coorsO,
            const float* __restrict__ wdFL,
            const unsigned short* __restrict__ ew2PL,
            const float* __restrict__ eb2L,
            const unsigned short* __restrict__ cw1PL,
            const float* __restrict__ cb1PL,
            const float* __restrict__ cw2PL,
            const float* __restrict__ cb2L,
            const float* __restrict__ lnbL,
            float* __restrict__ miBuf, float* __restrict__ deltaBuf,
            int Nn, int itpg, int njt) {
    __shared__ unsigned short bS[32 * BPITCH];        // 17.7 KB  bf16 b-rows (j-tile)
    __shared__ float          aSf[8 * APITCH];        //  8.8 KB  f32 a-rows (i-tile)
    __shared__ float          wdS[KP];                //  1.1 KB  f32 dist-weights
    __shared__ float          cjS[32 * 3];            //  j-tile coords
    __shared__ float          cbS[128], cwS[128];     //  stage-3 biases/weights
    __shared__ unsigned short mT[4][32 * 36];         //  9.2 KB  per-wave m^T

    int bid = blockIdx.x;
    int g   = bid / (itpg * njt);
    int r   = bid % (itpg * njt);
    int it  = r / njt;
    int jt  = r % njt;

    int tid  = threadIdx.x;
    int wave = tid >> 6, lane = tid & 63, half = lane >> 5, e = lane & 31;

    int j0  = jt * 32;
    int njr = Nn - j0; if (njr > 32) njr = 32;
    int i0  = it * 8;
    int nir = Nn - i0; if (nir > 8) nir = 8;

    // ---- coalesced staging ----
    {
        const unsigned int* src = (const unsigned int*)(bH + (size_t)(g * Nn + j0) * KP);
        unsigned int* dst = (unsigned int*)bS;
        int tot = njr * 136;
        for (int x = tid; x < tot; x += 256) {
            int rr = x / 136, c = x % 136;
            dst[rr * (BPITCH / 2) + c] = src[rr * 136 + c];
        }
        const unsigned short* asrc = aH + (size_t)(g * Nn + i0) * KP;
        int at = nir * KP;
        for (int x = tid; x < at; x += 256) {
            int rr = x / KP, k = x % KP;
            aSf[rr * APITCH + k] = bf16_up(asrc[rr * KP + k]);
        }
        for (int x = tid; x < KP; x += 256) wdS[x] = wdFL[x];
        if (tid < njr * 3) cjS[tid] = coorsO[(g * Nn + j0) * 3 + tid];
        if (tid < 128) { cbS[tid] = cb1PL[tid]; cwS[tid] = cw2PL[tid]; }
    }
    __syncthreads();

    float eb2v = eb2L[e];
    float beta = lnbL[0];
    float cb2v = cb2L[0];

    int  jc     = (e < njr) ? e : (njr - 1);
    bool jvalid = (e < njr);
    float cjx = cjS[jc * 3 + 0], cjy = cjS[jc * 3 + 1], cjz = cjS[jc * 3 + 2];

    unsigned short* mW = &mT[wave][0];
    const unsigned short* bRow = bS + jc * BPITCH;

    for (int s = 0; s < 2; s++) {
        int il = wave * 2 + s;
        if (il >= nir) break;
        int i  = i0 + il;
        int gi = g * Nn + i;

        float cix = coorsO[gi * 3 + 0], ciy = coorsO[gi * 3 + 1], ciz = coorsO[gi * 3 + 2];
        float rx = cix - cjx, ry = ciy - cjy, rz = ciz - cjz;
        float dist = rx * rx + ry * ry + rz * rz;

        const float* aRowF = aSf + il * APITCH;

        // ---- stage 2: H build + 17 MFMAs ----
        f32x16 acc;
#pragma unroll
        for (int q = 0; q < 16; q++) acc[q] = 0.0f;

#pragma unroll
        for (int k0 = 0; k0 < NK0; k0++) {
            int ko = k0 * 16 + half * 8;
            uint2 b01 = *(const uint2*)(bRow + ko);
            uint2 b23 = *(const uint2*)(bRow + ko + 4);
            uint4v eu = *(const uint4v*)(ew2PL + ((size_t)k0 * 64 + lane) * 8);
            unsigned bw[4] = {b01.x, b01.y, b23.x, b23.y};
            uint4v hu;
#pragma unroll
            for (int p = 0; p < 4; p++) {
                float2 av = *(const float2*)(aRowF + ko + 2 * p);
                float2 wv = *(const float2*)(wdS + ko + 2 * p);
                float bL = __uint_as_float(bw[p] << 16);
                float bU = __uint_as_float(bw[p] & 0xFFFF0000u);
                float hL = silu_f(av.x + bL + dist * wv.x);
                float hU = silu_f(av.y + bU + dist * wv.y);
                hu[p] = __builtin_amdgcn_perm(__float_as_uint(hU), __float_as_uint(hL),
                                              0x07060302u);
            }
            acc = __builtin_amdgcn_mfma_f32_32x32x16_bf16(
                      __builtin_bit_cast(bf16x8, hu),
                      __builtin_bit_cast(bf16x8, eu), acc, 0, 0, 0);
        }

        // ---- stage 2 epilogue: m_ij = silu(acc + eb2[n]); m_i; stage m^T ----
        float miAcc = 0.0f;
        float mv[16];
#pragma unroll
        for (int q = 0; q < 16; q++) {
            int row = (q & 3) + 8 * (q >> 2) + 4 * half;   // j within tile
            float m = silu_f(acc[q] + eb2v);
            m = (j0 + row < Nn) ? m : 0.0f;
            mv[q] = m;
            miAcc += m;
        }
#pragma unroll
        for (int q = 0; q < 4; q++) {
            unsigned lo = __builtin_amdgcn_perm(__float_as_uint(mv[q * 4 + 1]),
                                                __float_as_uint(mv[q * 4 + 0]), 0x07060302u);
            unsigned hi = __builtin_amdgcn_perm(__float_as_uint(mv[q * 4 + 3]),
                                                __float_as_uint(mv[q * 4 + 2]), 0x07060302u);
            int row0 = 8 * q + 4 * half;
            *(uint2*)&mW[e * 36 + row0] = make_uint2(lo, hi);
        }

        miAcc += __shfl_xor(miAcc, 32, 64);
        if (half == 0) atomicAdd(&miBuf[gi * MDIM + e], miAcc);

        // ---- stage 3: B-frags (m^T) from LDS, 8 MFMAs, w reduction ----
        bf16x8 bq[2];
#pragma unroll
        for (int k0 = 0; k0 < 2; k0++) {
            uint4v t;
#pragma unroll
            for (int p = 0; p < 4; p++) {
                unsigned v0 = mW[(k0 * 16 + half * 8 + 2 * p    ) * 36 + e];
                unsigned v1 = mW[(k0 * 16 + half * 8 + 2 * p + 1) * 36 + e];
                t[p] = v0 | (v1 << 16);
            }
            bq[k0] = __builtin_bit_cast(bf16x8, t);
        }

        float wAcc = 0.0f;
#pragma unroll
        for (int mb = 0; mb < 4; mb++) {
            f32x16 sacc;
#pragma unroll
            for (int q = 0; q < 16; q++) sacc[q] = 0.0f;
#pragma unroll
            for (int k0 = 0; k0 < 2; k0++) {
                uint4v cu = *(const uint4v*)(cw1PL + ((size_t)(mb * 2 + k0) * 64 + lane) * 8);
                sacc = __builtin_amdgcn_mfma_f32_32x32x16_bf16(
                           __builtin_bit_cast(bf16x8, cu), bq[k0], sacc, 0, 0, 0);
            }
            const float* cb1q = cbS + (half * 4 + mb) * 16;
            const float* cw2q = cwS + (half * 4 + mb) * 16;
#pragma unroll
            for (int q = 0; q < 16; q++) {
                wAcc += silu_f(sacc[q] + cb1q[q]) * cw2q[q];
            }
        }
        wAcc += __shfl_xor(wAcc, 32, 64);
        float w = wAcc + cb2v;
        float nrm = sqrtf(dist);
        float scale = (w * 0.02f) * beta / fmaxf(nrm, 1e-8f);

        float dAx = 0.0f, dAy = 0.0f, dAz = 0.0f;
        if (jvalid && half == 0) {
            dAx = scale * rx; dAy = scale * ry; dAz = scale * rz;
        }
#pragma unroll
        for (int m = 16; m >= 1; m >>= 1) {
            dAx += __shfl_xor(dAx, m, 64);
            dAy += __shfl_xor(dAy, m, 64);
            dAz += __shfl_xor(dAz, m, 64);
        }
        if (lane == 0) {
            atomicAdd(&deltaBuf[gi * 3 + 0], dAx);
            atomicAdd(&deltaBuf[gi * 3 + 1], dAy);
            atomicAdd(&deltaBuf[gi * 3 + 2], dAz);
        }
    }
}

// ---------------------------------------------------------------------------
// Node update: f_out = silu([f, m_i] @ nw1 + nb1) @ nw2 + nb2 + f ; c += delta
// ---------------------------------------------------------------------------
__global__ __launch_bounds__(128)
void k_node(const float* __restrict__ featsIn, const float* __restrict__ coorsIn,
            const float* __restrict__ miBuf, const float* __restrict__ deltaBuf,
            const float* __restrict__ nw1L, const float* __restrict__ nb1L,
            const float* __restrict__ nw2L, const float* __restrict__ nb2L,
            float* __restrict__ featsOut, float* __restrict__ coorsOut,
            float* __restrict__ outFinal, int alongL, int isLast) {
    __shared__ float xS[DIM + MDIM];
    __shared__ float hS[NH];
    int nf = blockIdx.x;
    int gnode;
    if (alongL) {
        int b = nf / (LL * NN);
        int rem = nf % (LL * NN);
        int l = rem / NN, n = rem % NN;
        gnode = (b * NN + n) * LL + l;
    } else {
        gnode = nf;
    }
    int t = threadIdx.x;
    if (t < DIM) xS[t] = featsIn[nf * DIM + t];
    else if (t < DIM + MDIM) xS[t] = miBuf[gnode * MDIM + (t - DIM)];
    __syncthreads();

    float s = nb1L[t];
#pragma unroll
    for (int d = 0; d < DIM + MDIM; d++) s += xS[d] * nw1L[d * NH + t];
    hS[t] = silu_f(s);
    __syncthreads();

    if (t < DIM) {
        float o = nb2L[t] + xS[t];
#pragma unroll
        for (int k = 0; k < NH; k++) o += hS[k] * nw2L[k * DIM + t];
        featsOut[nf * DIM + t] = o;
    }
    if (t < 3) {
        float c = coorsIn[nf * 3 + t] + deltaBuf[gnode * 3 + t];
        if (isLast) outFinal[nf * 3 + t] = c;
        else        coorsOut[nf * 3 + t] = c;
    }
}

// ---------------------------------------------------------------------------
extern "C" void kernel_launch(void* const* d_in, const int* in_sizes, int n_in,
                              void* d_out, int out_size, void* d_ws, size_t ws_size,
                              hipStream_t stream) {
    (void)in_sizes; (void)n_in; (void)out_size; (void)ws_size;

    const int*   tokens  = (const int*)d_in[0];
    const float* cords   = (const float*)d_in[1];
    const float* tok_emb = (const float*)d_in[2];
    const float* pos_emb = (const float*)d_in[3];
    const float* ew1 = (const float*)d_in[4];
    const float* eb1 = (const float*)d_in[5];
    const float* ew2 = (const float*)d_in[6];
    const float* eb2 = (const float*)d_in[7];
    const float* cw1 = (const float*)d_in[8];
    const float* cb1 = (const float*)d_in[9];
    const float* cw2 = (const float*)d_in[10];
    const float* cb2 = (const float*)d_in[11];
    const float* nw1 = (const float*)d_in[12];
    const float* nb1 = (const float*)d_in[13];
    const float* nw2 = (const float*)d_in[14];
    const float* nb2 = (const float*)d_in[15];
    /* d_in[16] = ln_g : multiplied by zeros in the reference -> unused */
    const float* lnb = (const float*)d_in[17];

    // -------- workspace carve-up ----
    float* wf = (float*)d_ws;
    float* featsA = wf; wf += NNODE * DIM;
    float* featsB = wf; wf += NNODE * DIM;
    float* coorsA = wf; wf += NNODE * 3;
    float* coorsB = wf; wf += NNODE * 3;
    float* coorsO = wf; wf += NNODE * 3;
    float* miBuf  = wf; wf += NNODE * MDIM;
    float* deltaB = wf; wf += NNODE * 3;
    float* cb1P   = wf; wf += NLAY * 128;
    float* cw2P   = wf; wf += NLAY * 128;
    float* wdF    = wf; wf += NLAY * KP;

    unsigned short* wh = (unsigned short*)wf;
    unsigned short* aHb  = wh; wh += (size_t)NNODE * KP;
    unsigned short* bHb  = wh; wh += (size_t)NNODE * KP;
    unsigned short* ew2P = wh; wh += NLAY * NK0 * 512;
    unsigned short* cw1P = wh; wh += NLAY * 4096;

    k_prep<<<(NLAY * NK0 * 512 + 255) / 256, 256, 0, stream>>>(
        ew1, ew2, cw1, cb1, cw2, wdF, ew2P, cw1P, cb1P, cw2P);
    k_embed<<<(NNODE * DIM + 255) / 256, 256, 0, stream>>>(
        tokens, cords, tok_emb, pos_emb, featsA, coorsA);

    float* fIn = featsA; float* fOut = featsB;
    float* cIn = coorsA; float* cOut = coorsB;

    for (int L = 0; L < NLAY; L++) {
        int alongL = (L / 4) % 2;              // L0-3:N, L4-7:l, L8-11:N, L12-15:l
        int Nn   = alongL ? LL : NN;
        int njt  = alongL ? 3 : 1;
        int itpg = (Nn + 7) / 8;
        int groups = NNODE / Nn;

        k_pre<<<NNODE, 256, 0, stream>>>(
            fIn, cIn, ew1 + (size_t)L * EIN * EH, eb1 + L * EH, aHb, bHb,
            coorsO, miBuf, deltaB, alongL);

        k_edge<<<groups * itpg * njt, 256, 0, stream>>>(
            aHb, bHb, coorsO,
            wdF + L * KP, ew2P + (size_t)L * NK0 * 512, eb2 + L * MDIM,
            cw1P + (size_t)L * 4096, cb1P + L * 128, cw2P + L * 128,
            cb2 + L, lnb + L, miBuf, deltaB, Nn, itpg, njt);

        int isLast = (L == NLAY - 1);
        k_node<<<NNODE, 128, 0, stream>>>(
            fIn, cIn, miBuf, deltaB,
            nw1 + (size_t)L * (DIM + MDIM) * NH, nb1 + L * NH,
            nw2 + (size_t)L * NH * DIM, nb2 + L * DIM,
            fOut, cOut, (float*)d_out, alongL, isLast);

        float* tmp = fIn; fIn = fOut; fOut = tmp;
        tmp = cIn; cIn = cOut; cOut = tmp;
    }
}

// Round 4
// 1860.712 us; speedup vs baseline: 2.8114x; 1.5306x over previous
//
#include <hip/hip_runtime.h>
#include <math.h>

#define DIM   64
#define MDIM  32
#define NLAY  16
#define PAD   1
#define NB    2
#define LL    96
#define NN    23
#define NNODE (NB*LL*NN)   /* 4416 */
#define EIN   129
#define EH    258          /* EIN*2 */
#define KP    272          /* EH padded to 17*16 */
#define NK0   17
#define NH    128          /* DIM*2 */
#define BPITCH 276
#define APITCH 274
#define NOUT  516          /* 2*EH outs of the a/b GEMM */
#define NTILE 17           /* ceil(544/32) N-tiles for k_pre GEMM */

typedef __attribute__((ext_vector_type(8)))  short        bf16x8;
typedef __attribute__((ext_vector_type(16))) float        f32x16;
typedef __attribute__((ext_vector_type(4)))  unsigned int uint4v;

__device__ __forceinline__ float silu_f(float x) {
    // x * sigmoid(x) via v_exp + v_rcp (precision far beyond the 7.6e-2 threshold)
    float e = __expf(-x);
    return x * __builtin_amdgcn_rcpf(1.0f + e);
}
__device__ __forceinline__ unsigned short bf16_rn(float x) {
    unsigned u = __float_as_uint(x);
    u += 0x7FFF + ((u >> 16) & 1);
    return (unsigned short)(u >> 16);
}
__device__ __forceinline__ float bf16_up(unsigned short h) {
    return __uint_as_float(((unsigned)h) << 16);
}
__device__ __forceinline__ int inv_map(int gnode, int alongL) {
    if (alongL) {
        int g = gnode / LL, l = gnode % LL;
        int b = g / NN, n = g % NN;
        return (b * LL + l) * NN + n;
    }
    return gnode;
}

// ---------------------------------------------------------------------------
// Embedding init (canonical layout), copy coords.
// ---------------------------------------------------------------------------
__global__ void k_embed(const int* __restrict__ tokens,
                        const float* __restrict__ cords,
                        const float* __restrict__ tok_emb,
                        const float* __restrict__ pos_emb,
                        float* __restrict__ feats,
                        float* __restrict__ coors) {
    int idx = blockIdx.x * blockDim.x + threadIdx.x;
    if (idx < NNODE * DIM) {
        int node = idx / DIM, d = idx % DIM;
        int b = node / (LL * NN);
        int rem = node % (LL * NN);
        int n = rem % NN;
        int l = rem / NN;
        int t = tokens[b * LL + l];
        float f = tok_emb[t * DIM + d];
        if (t != PAD) f += pos_emb[(n + 2) * DIM + d];
        feats[idx] = f;
    }
    if (idx < NNODE * 3) coors[idx] = cords[idx];
}

// ---------------------------------------------------------------------------
// One-time weight prep into MFMA-fragment layouts (all layers).
//  ew1P[L][nt][ks][512] : B-frags for the a/b GEMM (K=64 d, N=544 padded outs)
//  ew2P / cw1P / cb1P / cw2P / wdF : as before
// ---------------------------------------------------------------------------
__global__ void k_prep(const float* __restrict__ ew1, const float* __restrict__ ew2,
                       const float* __restrict__ cw1, const float* __restrict__ cb1,
                       const float* __restrict__ cw2,
                       float* __restrict__ wdF, unsigned short* __restrict__ ew2P,
                       unsigned short* __restrict__ cw1P,
                       float* __restrict__ cb1P, float* __restrict__ cw2P,
                       unsigned short* __restrict__ ew1P) {
    int idx = blockIdx.x * blockDim.x + threadIdx.x;
    if (idx < NLAY * KP) {
        int L = idx / KP, k = idx % KP;
        float v = (k < EH) ? ew1[(size_t)L * EIN * EH + 128 * EH + k] : 0.0f;
        wdF[idx] = bf16_up(bf16_rn(v));
    }
    if (idx < NLAY * NK0 * 512) {
        int L = idx / (NK0 * 512); int r = idx % (NK0 * 512);
        int k0 = r / 512; int r2 = r % 512;
        int lane = r2 >> 3, j = r2 & 7;
        int k = k0 * 16 + (lane >> 5) * 8 + j;
        int n = lane & 31;
        float v = (k < EH) ? ew2[((size_t)L * EH + k) * MDIM + n] : 0.0f;
        ew2P[idx] = bf16_rn(v);
    }
    if (idx < NLAY * 4096) {
        int L = idx / 4096; int r = idx % 4096;
        int mb = r / 1024; int r2 = r % 1024;
        int k0 = r2 / 512; int r3 = r2 % 512;
        int lane = r3 >> 3, j = r3 & 7;
        int k = k0 * 16 + (lane >> 5) * 8 + j;
        int o = mb * 32 + (lane & 31);
        cw1P[idx] = bf16_rn(cw1[((size_t)L * MDIM + k) * NH + o]);
    }
    if (idx < NLAY * 128) {
        int L = idx / 128; int r = idx % 128;
        int hlf = r / 64; int r2 = r % 64;
        int mb = r2 / 16, reg = r2 % 16;
        int o = mb * 32 + (reg & 3) + 8 * (reg >> 2) + 4 * hlf;
        cb1P[idx] = cb1[L * NH + o];
        cw2P[idx] = cw2[L * NH + o];
    }
    if (idx < NLAY * NTILE * 4 * 512) {
        int L = idx / (NTILE * 4 * 512); int r = idx % (NTILE * 4 * 512);
        int nt = r / 2048; int r2 = r % 2048;
        int ks = r2 / 512; int r3 = r2 % 512;
        int lane = r3 >> 3, j = r3 & 7;
        int d = ks * 16 + (lane >> 5) * 8 + j;      // K index (feat dim, 0..63)
        int o = nt * 32 + (lane & 31);              // out col (0..543)
        float v = 0.0f;
        if (o < EH)           v = ew1[(size_t)L * EIN * EH + d * EH + o];
        else if (o < NOUT)    v = ew1[(size_t)L * EIN * EH + (DIM + d) * EH + (o - EH)];
        ew1P[idx] = bf16_rn(v);
    }
}

// ---------------------------------------------------------------------------
// k_pre (MFMA): 69 blocks x 128 threads (2 waves), 64 nodes/block.
// GEMM: feats(64 x 64) @ ew1P(64 x 544) -> a/b rows (bf16, gnode order).
// Also stages coorsO and zeroes miBuf/deltaBuf for this layer.
// ---------------------------------------------------------------------------
__global__ __launch_bounds__(128)
void k_pre(const float* __restrict__ feats, const float* __restrict__ coors,
           const unsigned short* __restrict__ ew1PL, const float* __restrict__ eb1L,
           unsigned short* __restrict__ aH, unsigned short* __restrict__ bH,
           float* __restrict__ coorsO, float* __restrict__ miBuf,
           float* __restrict__ deltaBuf, int alongL) {
    __shared__ unsigned short fS[64 * 72];   // [node][d] bf16, pitch 72 (16B-aligned rows)

    int g0  = blockIdx.x * 64;
    int tid = threadIdx.x;
    int wave = tid >> 6, lane = tid & 63, half = lane >> 5, e = lane & 31;

    // stage feats (bf16) for 64 nodes
    for (int i = 0; i < 32; i++) {
        int x = tid + 128 * i;               // 4096
        int node = x >> 6, d = x & 63;
        int nf = inv_map(g0 + node, alongL);
        fS[node * 72 + d] = bf16_rn(feats[nf * DIM + d]);
    }
    // coorsO + zero accumulators
    for (int x = tid; x < 64 * 3; x += 128) {
        int node = x / 3, c = x % 3;
        int nf = inv_map(g0 + node, alongL);
        coorsO[(g0 + node) * 3 + c] = coors[nf * 3 + c];
        deltaBuf[(g0 + node) * 3 + c] = 0.0f;
    }
    for (int x = tid; x < 64 * MDIM; x += 128)
        miBuf[g0 * MDIM + x] = 0.0f;
    // zero k-padding of aH/bH
    for (int x = tid; x < 64 * (KP - EH); x += 128) {
        int node = x / (KP - EH), c = EH + x % (KP - EH);
        aH[(size_t)(g0 + node) * KP + c] = 0;
        bH[(size_t)(g0 + node) * KP + c] = 0;
    }
    __syncthreads();

    // A-frags: this wave's 32-node M-tile, 4 K-steps
    uint4v afrag[4];
#pragma unroll
    for (int ks = 0; ks < 4; ks++) {
        int node = wave * 32 + e;
        afrag[ks] = *(const uint4v*)(fS + node * 72 + ks * 16 + half * 8);
    }

    for (int nt = 0; nt < NTILE; nt++) {
        f32x16 acc;
#pragma unroll
        for (int q = 0; q < 16; q++) acc[q] = 0.0f;
#pragma unroll
        for (int ks = 0; ks < 4; ks++) {
            uint4v bu = *(const uint4v*)(ew1PL + ((size_t)(nt * 4 + ks) * 512 + lane * 8));
            acc = __builtin_amdgcn_mfma_f32_32x32x16_bf16(
                      __builtin_bit_cast(bf16x8, afrag[ks]),
                      __builtin_bit_cast(bf16x8, bu), acc, 0, 0, 0);
        }
        int o = nt * 32 + e;
        float eb1v = (o < EH) ? eb1L[o] : 0.0f;
#pragma unroll
        for (int q = 0; q < 16; q++) {
            int row = (q & 3) + 8 * (q >> 2) + 4 * half;
            size_t node = g0 + wave * 32 + row;
            if (o < EH)        aH[node * KP + o]        = bf16_rn(acc[q] + eb1v);
            else if (o < NOUT) bH[node * KP + (o - EH)] = bf16_rn(acc[q]);
        }
    }
}

// ---------------------------------------------------------------------------
// MFMA edge kernel. Block = (group, 8-i-tile, 32-j-tile). LDS-staged inputs.
// ---------------------------------------------------------------------------
__global__ __launch_bounds__(256, 3)
void k_edge(const unsigned short* __restrict__ aH,
            const unsigned short* __restrict__ bH,
            const float* __restrict__ coorsO,
            const float* __restrict__ wdFL,
            const unsigned short* __restrict__ ew2PL,
            const float* __restrict__ eb2L,
            const unsigned short* __restrict__ cw1PL,
            const float* __restrict__ cb1PL,
            const float* __restrict__ cw2PL,
            const float* __restrict__ cb2L,
            const float* __restrict__ lnbL,
            float* __restrict__ miBuf, float* __restrict__ deltaBuf,
            int Nn, int itpg, int njt) {
    __shared__ unsigned short bS[32 * BPITCH];
    __shared__ float          aSf[8 * APITCH];
    __shared__ float          wdS[KP];
    __shared__ float          cjS[32 * 3];
    __shared__ float          cbS[128], cwS[128];
    __shared__ unsigned short mT[4][32 * 36];

    int bid = blockIdx.x;
    int g   = bid / (itpg * njt);
    int r   = bid % (itpg * njt);
    int it  = r / njt;
    int jt  = r % njt;

    int tid  = threadIdx.x;
    int wave = tid >> 6, lane = tid & 63, half = lane >> 5, e = lane & 31;

    int j0  = jt * 32;
    int njr = Nn - j0; if (njr > 32) njr = 32;
    int i0  = it * 8;
    int nir = Nn - i0; if (nir > 8) nir = 8;

    {
        const unsigned int* src = (const unsigned int*)(bH + (size_t)(g * Nn + j0) * KP);
        unsigned int* dst = (unsigned int*)bS;
        int tot = njr * 136;
        for (int x = tid; x < tot; x += 256) {
            int rr = x / 136, c = x % 136;
            dst[rr * (BPITCH / 2) + c] = src[rr * 136 + c];
        }
        const unsigned short* asrc = aH + (size_t)(g * Nn + i0) * KP;
        int at = nir * KP;
        for (int x = tid; x < at; x += 256) {
            int rr = x / KP, k = x % KP;
            aSf[rr * APITCH + k] = bf16_up(asrc[rr * KP + k]);
        }
        for (int x = tid; x < KP; x += 256) wdS[x] = wdFL[x];
        if (tid < njr * 3) cjS[tid] = coorsO[(g * Nn + j0) * 3 + tid];
        if (tid < 128) { cbS[tid] = cb1PL[tid]; cwS[tid] = cw2PL[tid]; }
    }
    __syncthreads();

    float eb2v = eb2L[e];
    float beta = lnbL[0];
    float cb2v = cb2L[0];

    int  jc     = (e < njr) ? e : (njr - 1);
    bool jvalid = (e < njr);
    float cjx = cjS[jc * 3 + 0], cjy = cjS[jc * 3 + 1], cjz = cjS[jc * 3 + 2];

    unsigned short* mW = &mT[wave][0];
    const unsigned short* bRow = bS + jc * BPITCH;

    for (int s = 0; s < 2; s++) {
        int il = wave * 2 + s;
        if (il >= nir) break;
        int i  = i0 + il;
        int gi = g * Nn + i;

        float cix = coorsO[gi * 3 + 0], ciy = coorsO[gi * 3 + 1], ciz = coorsO[gi * 3 + 2];
        float rx = cix - cjx, ry = ciy - cjy, rz = ciz - cjz;
        float dist = rx * rx + ry * ry + rz * rz;

        const float* aRowF = aSf + il * APITCH;

        f32x16 acc;
#pragma unroll
        for (int q = 0; q < 16; q++) acc[q] = 0.0f;

#pragma unroll
        for (int k0 = 0; k0 < NK0; k0++) {
            int ko = k0 * 16 + half * 8;
            uint2 b01 = *(const uint2*)(bRow + ko);
            uint2 b23 = *(const uint2*)(bRow + ko + 4);
            uint4v eu = *(const uint4v*)(ew2PL + ((size_t)k0 * 64 + lane) * 8);
            unsigned bw[4] = {b01.x, b01.y, b23.x, b23.y};
            uint4v hu;
#pragma unroll
            for (int p = 0; p < 4; p++) {
                float2 av = *(const float2*)(aRowF + ko + 2 * p);
                float2 wv = *(const float2*)(wdS + ko + 2 * p);
                float bL = __uint_as_float(bw[p] << 16);
                float bU = __uint_as_float(bw[p] & 0xFFFF0000u);
                float hL = silu_f(av.x + bL + dist * wv.x);
                float hU = silu_f(av.y + bU + dist * wv.y);
                hu[p] = __builtin_amdgcn_perm(__float_as_uint(hU), __float_as_uint(hL),
                                              0x07060302u);
            }
            acc = __builtin_amdgcn_mfma_f32_32x32x16_bf16(
                      __builtin_bit_cast(bf16x8, hu),
                      __builtin_bit_cast(bf16x8, eu), acc, 0, 0, 0);
        }

        float miAcc = 0.0f;
        float mv[16];
#pragma unroll
        for (int q = 0; q < 16; q++) {
            int row = (q & 3) + 8 * (q >> 2) + 4 * half;
            float m = silu_f(acc[q] + eb2v);
            m = (j0 + row < Nn) ? m : 0.0f;
            mv[q] = m;
            miAcc += m;
        }
#pragma unroll
        for (int q = 0; q < 4; q++) {
            unsigned lo = __builtin_amdgcn_perm(__float_as_uint(mv[q * 4 + 1]),
                                                __float_as_uint(mv[q * 4 + 0]), 0x07060302u);
            unsigned hi = __builtin_amdgcn_perm(__float_as_uint(mv[q * 4 + 3]),
                                                __float_as_uint(mv[q * 4 + 2]), 0x07060302u);
            int row0 = 8 * q + 4 * half;
            *(uint2*)&mW[e * 36 + row0] = make_uint2(lo, hi);
        }

        miAcc += __shfl_xor(miAcc, 32, 64);
        if (half == 0) atomicAdd(&miBuf[gi * MDIM + e], miAcc);

        bf16x8 bq[2];
#pragma unroll
        for (int k0 = 0; k0 < 2; k0++) {
            uint4v t;
#pragma unroll
            for (int p = 0; p < 4; p++) {
                unsigned v0 = mW[(k0 * 16 + half * 8 + 2 * p    ) * 36 + e];
                unsigned v1 = mW[(k0 * 16 + half * 8 + 2 * p + 1) * 36 + e];
                t[p] = v0 | (v1 << 16);
            }
            bq[k0] = __builtin_bit_cast(bf16x8, t);
        }

        float wAcc = 0.0f;
#pragma unroll
        for (int mb = 0; mb < 4; mb++) {
            f32x16 sacc;
#pragma unroll
            for (int q = 0; q < 16; q++) sacc[q] = 0.0f;
#pragma unroll
            for (int k0 = 0; k0 < 2; k0++) {
                uint4v cu = *(const uint4v*)(cw1PL + ((size_t)(mb * 2 + k0) * 64 + lane) * 8);
                sacc = __builtin_amdgcn_mfma_f32_32x32x16_bf16(
                           __builtin_bit_cast(bf16x8, cu), bq[k0], sacc, 0, 0, 0);
            }
            const float* cb1q = cbS + (half * 4 + mb) * 16;
            const float* cw2q = cwS + (half * 4 + mb) * 16;
#pragma unroll
            for (int q = 0; q < 16; q++) {
                wAcc += silu_f(sacc[q] + cb1q[q]) * cw2q[q];
            }
        }
        wAcc += __shfl_xor(wAcc, 32, 64);
        float w = wAcc + cb2v;
        float nrm = sqrtf(dist);
        float scale = (w * 0.02f) * beta * __builtin_amdgcn_rcpf(fmaxf(nrm, 1e-8f));

        float dAx = 0.0f, dAy = 0.0f, dAz = 0.0f;
        if (jvalid && half == 0) {
            dAx = scale * rx; dAy = scale * ry; dAz = scale * rz;
        }
#pragma unroll
        for (int m = 16; m >= 1; m >>= 1) {
            dAx += __shfl_xor(dAx, m, 64);
            dAy += __shfl_xor(dAy, m, 64);
            dAz += __shfl_xor(dAz, m, 64);
        }
        if (lane == 0) {
            atomicAdd(&deltaBuf[gi * 3 + 0], dAx);
            atomicAdd(&deltaBuf[gi * 3 + 1], dAy);
            atomicAdd(&deltaBuf[gi * 3 + 2], dAz);
        }
    }
}

// ---------------------------------------------------------------------------
// k_node (tiled): 138 blocks x 256 threads, 32 nodes/block.
// h = silu(nw1^T x + nb1); out = nw2^T h + nb2 + f ; c += delta
// ---------------------------------------------------------------------------
__global__ __launch_bounds__(256)
void k_node(const float* __restrict__ featsIn, const float* __restrict__ coorsIn,
            const float* __restrict__ miBuf, const float* __restrict__ deltaBuf,
            const float* __restrict__ nw1L, const float* __restrict__ nb1L,
            const float* __restrict__ nw2L, const float* __restrict__ nb2L,
            float* __restrict__ featsOut, float* __restrict__ coorsOut,
            float* __restrict__ outFinal, int alongL, int isLast) {
    __shared__ float xT[96 * 36];    // [d][node], pitch 36 (float4-aligned)
    __shared__ float hT[128 * 36];   // [h][node]

    int g0  = blockIdx.x * 32;
    int tid = threadIdx.x;

    for (int i = 0; i < 8; i++) {
        int x = tid + 256 * i;                 // 2048 = 32 nodes x 64 d
        int node = x >> 6, d = x & 63;
        int nf = inv_map(g0 + node, alongL);
        xT[d * 36 + node] = featsIn[nf * DIM + d];
    }
    for (int i = 0; i < 4; i++) {
        int x = tid + 256 * i;                 // 1024 = 32 x 32
        int node = x >> 5, d = x & 31;
        xT[(DIM + d) * 36 + node] = miBuf[(g0 + node) * MDIM + d];
    }
    __syncthreads();

    // phase 1: 128 h-outs x 2 groups of 16 nodes
    {
        int h = tid & 127, grp = tid >> 7;
        float acc[16];
        float b1 = nb1L[h];
#pragma unroll
        for (int n = 0; n < 16; n++) acc[n] = b1;
        for (int d = 0; d < DIM + MDIM; d++) {
            float w = nw1L[d * NH + h];
            const float4* fr = (const float4*)&xT[d * 36 + grp * 16];
#pragma unroll
            for (int v = 0; v < 4; v++) {
                float4 f4 = fr[v];
                acc[v * 4 + 0] = fmaf(f4.x, w, acc[v * 4 + 0]);
                acc[v * 4 + 1] = fmaf(f4.y, w, acc[v * 4 + 1]);
                acc[v * 4 + 2] = fmaf(f4.z, w, acc[v * 4 + 2]);
                acc[v * 4 + 3] = fmaf(f4.w, w, acc[v * 4 + 3]);
            }
        }
#pragma unroll
        for (int n = 0; n < 16; n++)
            hT[h * 36 + grp * 16 + n] = silu_f(acc[n]);
    }
    __syncthreads();

    // phase 2: 64 o-outs x 4 groups of 8 nodes
    {
        int o = tid & 63, g4 = tid >> 6;
        float acc2[8];
        float b2 = nb2L[o];
#pragma unroll
        for (int n = 0; n < 8; n++) acc2[n] = b2;
        for (int k = 0; k < NH; k++) {
            float w = nw2L[k * DIM + o];
            const float4* hr = (const float4*)&hT[k * 36 + g4 * 8];
#pragma unroll
            for (int v = 0; v < 2; v++) {
                float4 h4 = hr[v];
                acc2[v * 4 + 0] = fmaf(h4.x, w, acc2[v * 4 + 0]);
                acc2[v * 4 + 1] = fmaf(h4.y, w, acc2[v * 4 + 1]);
                acc2[v * 4 + 2] = fmaf(h4.z, w, acc2[v * 4 + 2]);
                acc2[v * 4 + 3] = fmaf(h4.w, w, acc2[v * 4 + 3]);
            }
        }
#pragma unroll
        for (int n = 0; n < 8; n++) {
            int node = g4 * 8 + n;
            int nf = inv_map(g0 + node, alongL);
            featsOut[nf * DIM + o] = acc2[n] + xT[o * 36 + node];
        }
    }
    if (tid < 32 * 3) {
        int node = tid / 3, c = tid % 3;
        int nf = inv_map(g0 + node, alongL);
        float cv = coorsIn[nf * 3 + c] + deltaBuf[(g0 + node) * 3 + c];
        if (isLast) outFinal[nf * 3 + c] = cv;
        else        coorsOut[nf * 3 + c] = cv;
    }
}

// ---------------------------------------------------------------------------
extern "C" void kernel_launch(void* const* d_in, const int* in_sizes, int n_in,
                              void* d_out, int out_size, void* d_ws, size_t ws_size,
                              hipStream_t stream) {
    (void)in_sizes; (void)n_in; (void)out_size; (void)ws_size;

    const int*   tokens  = (const int*)d_in[0];
    const float* cords   = (const float*)d_in[1];
    const float* tok_emb = (const float*)d_in[2];
    const float* pos_emb = (const float*)d_in[3];
    const float* ew1 = (const float*)d_in[4];
    const float* eb1 = (const float*)d_in[5];
    const float* ew2 = (const float*)d_in[6];
    const float* eb2 = (const float*)d_in[7];
    const float* cw1 = (const float*)d_in[8];
    const float* cb1 = (const float*)d_in[9];
    const float* cw2 = (const float*)d_in[10];
    const float* cb2 = (const float*)d_in[11];
    const float* nw1 = (const float*)d_in[12];
    const float* nb1 = (const float*)d_in[13];
    const float* nw2 = (const float*)d_in[14];
    const float* nb2 = (const float*)d_in[15];
    /* d_in[16] = ln_g : multiplied by zeros in the reference -> unused */
    const float* lnb = (const float*)d_in[17];

    float* wf = (float*)d_ws;
    float* featsA = wf; wf += NNODE * DIM;
    float* featsB = wf; wf += NNODE * DIM;
    float* coorsA = wf; wf += NNODE * 3;
    float* coorsB = wf; wf += NNODE * 3;
    float* coorsO = wf; wf += NNODE * 3;
    float* miBuf  = wf; wf += NNODE * MDIM;
    float* deltaB = wf; wf += NNODE * 3;
    float* cb1P   = wf; wf += NLAY * 128;
    float* cw2P   = wf; wf += NLAY * 128;
    float* wdF    = wf; wf += NLAY * KP;

    unsigned short* wh = (unsigned short*)wf;
    unsigned short* aHb  = wh; wh += (size_t)NNODE * KP;
    unsigned short* bHb  = wh; wh += (size_t)NNODE * KP;
    unsigned short* ew2P = wh; wh += NLAY * NK0 * 512;
    unsigned short* cw1P = wh; wh += NLAY * 4096;
    unsigned short* ew1P = wh; wh += (size_t)NLAY * NTILE * 4 * 512;

    int prepN = NLAY * NTILE * 4 * 512;
    k_prep<<<(prepN + 255) / 256, 256, 0, stream>>>(
        ew1, ew2, cw1, cb1, cw2, wdF, ew2P, cw1P, cb1P, cw2P, ew1P);
    k_embed<<<(NNODE * DIM + 255) / 256, 256, 0, stream>>>(
        tokens, cords, tok_emb, pos_emb, featsA, coorsA);

    float* fIn = featsA; float* fOut = featsB;
    float* cIn = coorsA; float* cOut = coorsB;

    for (int L = 0; L < NLAY; L++) {
        int alongL = (L / 4) % 2;
        int Nn   = alongL ? LL : NN;
        int njt  = alongL ? 3 : 1;
        int itpg = (Nn + 7) / 8;
        int groups = NNODE / Nn;

        k_pre<<<NNODE / 64, 128, 0, stream>>>(
            fIn, cIn, ew1P + (size_t)L * NTILE * 4 * 512, eb1 + L * EH,
            aHb, bHb, coorsO, miBuf, deltaB, alongL);

        k_edge<<<groups * itpg * njt, 256, 0, stream>>>(
            aHb, bHb, coorsO,
            wdF + L * KP, ew2P + (size_t)L * NK0 * 512, eb2 + L * MDIM,
            cw1P + (size_t)L * 4096, cb1P + L * 128, cw2P + L * 128,
            cb2 + L, lnb + L, miBuf, deltaB, Nn, itpg, njt);

        int isLast = (L == NLAY - 1);
        k_node<<<NNODE / 32, 256, 0, stream>>>(
            fIn, cIn, miBuf, deltaB,
            nw1 + (size_t)L * (DIM + MDIM) * NH, nb1 + L * NH,
            nw2 + (size_t)L * NH * DIM, nb2 + L * DIM,
            fOut, cOut, (float*)d_out, alongL, isLast);

        float* tmp = fIn; fIn = fOut; fOut = tmp;
        tmp = cIn; cIn = cOut; cOut = tmp;
    }
}

// Round 5
// 1054.963 us; speedup vs baseline: 4.9587x; 1.7638x over previous
//
#include <hip/hip_runtime.h>
#include <math.h>

#define DIM   64
#define MDIM  32
#define NLAY  16
#define PAD   1
#define NB    2
#define LL    96
#define NN    23
#define NNODE (NB*LL*NN)   /* 4416 */
#define EIN   129
#define EH    258          /* EIN*2 */
#define KP    272          /* EH padded to 17*16 */
#define NK0   17
#define NH    128          /* DIM*2 */
#define BPITCH 276
#define APITCH 274
#define NOUT  516          /* 2*EH outs of the a/b GEMM */
#define NTILE 17           /* ceil(544/32) N-tiles for pre GEMM */
#define XP    104          /* xS pitch shorts (52 dw -> 4-way ok, 16B rows) */
#define HP    136          /* hS pitch shorts (68 dw -> 4-way ok, 16B rows) */
#define OP    560          /* outS pitch shorts */

typedef __attribute__((ext_vector_type(8)))  short        bf16x8;
typedef __attribute__((ext_vector_type(16))) float        f32x16;
typedef __attribute__((ext_vector_type(4)))  unsigned int uint4v;

__device__ __forceinline__ float silu_f(float x) {
    float e = __expf(-x);
    return x * __builtin_amdgcn_rcpf(1.0f + e);
}
__device__ __forceinline__ unsigned short bf16_rn(float x) {
    unsigned u = __float_as_uint(x);
    u += 0x7FFF + ((u >> 16) & 1);
    return (unsigned short)(u >> 16);
}
__device__ __forceinline__ float bf16_up(unsigned short h) {
    return __uint_as_float(((unsigned)h) << 16);
}
// canonical nf -> orientation gnode
__device__ __forceinline__ int fwd_map(int nf, int alongL) {
    if (alongL) {
        int b = nf / (LL * NN);
        int rem = nf % (LL * NN);
        int l = rem / NN, n = rem % NN;
        return (b * NN + n) * LL + l;
    }
    return nf;
}
// orientation gnode -> canonical nf
__device__ __forceinline__ int inv_map(int gnode, int alongL) {
    if (alongL) {
        int g = gnode / LL, l = gnode % LL;
        int b = g / NN, n = g % NN;
        return (b * LL + l) * NN + n;
    }
    return gnode;
}

// ---------------------------------------------------------------------------
__global__ void k_embed(const int* __restrict__ tokens,
                        const float* __restrict__ tok_emb,
                        const float* __restrict__ pos_emb,
                        float* __restrict__ feats) {
    int idx = blockIdx.x * blockDim.x + threadIdx.x;
    if (idx < NNODE * DIM) {
        int node = idx / DIM, d = idx % DIM;
        int b = node / (LL * NN);
        int rem = node % (LL * NN);
        int n = rem % NN;
        int l = rem / NN;
        int t = tokens[b * LL + l];
        float f = tok_emb[t * DIM + d];
        if (t != PAD) f += pos_emb[(n + 2) * DIM + d];
        feats[idx] = f;
    }
}

// ---------------------------------------------------------------------------
// One-time weight prep into MFMA-fragment layouts (all layers).
// ---------------------------------------------------------------------------
__global__ void k_prep(const float* __restrict__ ew1, const float* __restrict__ ew2,
                       const float* __restrict__ cw1, const float* __restrict__ cb1,
                       const float* __restrict__ cw2,
                       const float* __restrict__ nw1, const float* __restrict__ nw2,
                       float* __restrict__ wdF, unsigned short* __restrict__ ew2P,
                       unsigned short* __restrict__ cw1P,
                       float* __restrict__ cb1P, float* __restrict__ cw2P,
                       unsigned short* __restrict__ ew1P,
                       unsigned short* __restrict__ nw1P,
                       unsigned short* __restrict__ nw2P) {
    int idx = blockIdx.x * blockDim.x + threadIdx.x;
    if (idx < NLAY * KP) {
        int L = idx / KP, k = idx % KP;
        float v = (k < EH) ? ew1[(size_t)L * EIN * EH + 128 * EH + k] : 0.0f;
        wdF[idx] = bf16_up(bf16_rn(v));
    }
    if (idx < NLAY * NK0 * 512) {
        int L = idx / (NK0 * 512); int r = idx % (NK0 * 512);
        int k0 = r / 512; int r2 = r % 512;
        int lane = r2 >> 3, j = r2 & 7;
        int k = k0 * 16 + (lane >> 5) * 8 + j;
        int n = lane & 31;
        float v = (k < EH) ? ew2[((size_t)L * EH + k) * MDIM + n] : 0.0f;
        ew2P[idx] = bf16_rn(v);
    }
    if (idx < NLAY * 4096) {
        int L = idx / 4096; int r = idx % 4096;
        int mb = r / 1024; int r2 = r % 1024;
        int k0 = r2 / 512; int r3 = r2 % 512;
        int lane = r3 >> 3, j = r3 & 7;
        int k = k0 * 16 + (lane >> 5) * 8 + j;
        int o = mb * 32 + (lane & 31);
        cw1P[idx] = bf16_rn(cw1[((size_t)L * MDIM + k) * NH + o]);
    }
    if (idx < NLAY * 128) {
        int L = idx / 128; int r = idx % 128;
        int hlf = r / 64; int r2 = r % 64;
        int mb = r2 / 16, reg = r2 % 16;
        int o = mb * 32 + (reg & 3) + 8 * (reg >> 2) + 4 * hlf;
        cb1P[idx] = cb1[L * NH + o];
        cw2P[idx] = cw2[L * NH + o];
    }
    if (idx < NLAY * NTILE * 4 * 512) {
        int L = idx / (NTILE * 4 * 512); int r = idx % (NTILE * 4 * 512);
        int nt = r / 2048; int r2 = r % 2048;
        int ks = r2 / 512; int r3 = r2 % 512;
        int lane = r3 >> 3, j = r3 & 7;
        int d = ks * 16 + (lane >> 5) * 8 + j;
        int o = nt * 32 + (lane & 31);
        float v = 0.0f;
        if (o < EH)        v = ew1[(size_t)L * EIN * EH + d * EH + o];
        else if (o < NOUT) v = ew1[(size_t)L * EIN * EH + (DIM + d) * EH + (o - EH)];
        ew1P[idx] = bf16_rn(v);
    }
    if (idx < NLAY * 4 * 6 * 512) {
        int L = idx / 12288; int r = idx % 12288;
        int nt = r / 3072; int r2 = r % 3072;
        int ks = r2 / 512; int r3 = r2 % 512;
        int lane = r3 >> 3, j = r3 & 7;
        int k = ks * 16 + (lane >> 5) * 8 + j;      // 0..95
        int n = nt * 32 + (lane & 31);              // 0..127
        nw1P[idx] = bf16_rn(nw1[((size_t)L * (DIM + MDIM) + k) * NH + n]);
    }
    if (idx < NLAY * 2 * 8 * 512) {
        int L = idx / 8192; int r = idx % 8192;
        int nt = r / 4096; int r2 = r % 4096;
        int ks = r2 / 512; int r3 = r2 % 512;
        int lane = r3 >> 3, j = r3 & 7;
        int k = ks * 16 + (lane >> 5) * 8 + j;      // 0..127
        int n = nt * 32 + (lane & 31);              // 0..63
        nw2P[idx] = bf16_rn(nw2[((size_t)L * NH + k) * DIM + n]);
    }
}

// ---------------------------------------------------------------------------
// Fused node-MLP(L) + pre(L+1). 32 canonical nodes per block, 256 threads.
//  doNode: h = silu([f,mi]@nw1+nb1); f' = h@nw2+nb2+f  (MFMA, bf16)
//  always: a|b = f'@ew1P(+eb1) assembled in LDS, coalesced b128 global stores.
//  Also: coors update + zero next-layer accumulators (ping-pong).
// ---------------------------------------------------------------------------
__global__ __launch_bounds__(256)
void k_np(const float* __restrict__ fIn, const float* __restrict__ coSrc,
          const float* __restrict__ miL, const float* __restrict__ dL,
          const unsigned short* __restrict__ nw1PL, const float* __restrict__ nb1L,
          const unsigned short* __restrict__ nw2PL, const float* __restrict__ nb2L,
          const unsigned short* __restrict__ ew1PL, const float* __restrict__ eb1L,
          float* __restrict__ fOut, float* __restrict__ coDst,
          float* __restrict__ miNext, float* __restrict__ dNext,
          unsigned short* __restrict__ aH, unsigned short* __restrict__ bH,
          int aL0, int aL1, int doNode) {
    __shared__ unsigned short xS[32 * XP];     //  6.5 KB [node][f(64)|mi(32)]
    __shared__ unsigned short hS[32 * HP];     //  8.5 KB [node][h 128]
    __shared__ unsigned short outS[32 * OP];   // 35.0 KB [node][a 272 | b 272]
    __shared__ int gsrcS[32], gdstS[32];

    int n0  = blockIdx.x * 32;
    int tid = threadIdx.x;
    int wave = tid >> 6, lane = tid & 63, half = lane >> 5, e = lane & 31;

    if (tid < 32) {
        gsrcS[tid] = fwd_map(n0 + tid, aL0);
        gdstS[tid] = fwd_map(n0 + tid, aL1);
    }
    __syncthreads();

    // ---- staging ----
    for (int i = 0; i < 8; i++) {
        int x = tid + 256 * i;                 // 2048 = 32x64
        int node = x >> 6, d = x & 63;
        xS[node * XP + d] = bf16_rn(fIn[(n0 + node) * DIM + d]);
    }
    if (doNode) {
        for (int i = 0; i < 4; i++) {
            int x = tid + 256 * i;             // 1024 = 32x32
            int node = x >> 5, d = x & 31;
            xS[node * XP + DIM + d] = bf16_rn(miL[(size_t)gsrcS[node] * MDIM + d]);
        }
    }
    // zero a-row K-pads (cols 258..271)
    for (int x = tid; x < 32 * 14; x += 256) {
        int node = x / 14, c = EH + x % 14;
        outS[node * OP + c] = 0;
    }
    // coors update + zero next accumulators
    if (tid < 96) {
        int node = tid / 3, c = tid % 3;
        int gs = gsrcS[node], gd = gdstS[node];
        float cv = coSrc[gs * 3 + c] + (doNode ? dL[gs * 3 + c] : 0.0f);
        coDst[gd * 3 + c] = cv;
        dNext[gd * 3 + c] = 0.0f;
    }
    for (int i = 0; i < 4; i++) {
        int x = tid + 256 * i;
        int node = x >> 5, d = x & 31;
        miNext[(size_t)gdstS[node] * MDIM + d] = 0.0f;
    }
    __syncthreads();

    if (doNode) {
        // ---- GEMM1: X(32x96) @ nw1(96x128), wave -> n-tile ----
        {
            int nt = wave;
            f32x16 acc;
#pragma unroll
            for (int q = 0; q < 16; q++) acc[q] = 0.0f;
#pragma unroll
            for (int ks = 0; ks < 6; ks++) {
                uint4v au = *(const uint4v*)(xS + e * XP + ks * 16 + half * 8);
                uint4v bu = *(const uint4v*)(nw1PL + ((size_t)(nt * 6 + ks) * 512 + lane * 8));
                acc = __builtin_amdgcn_mfma_f32_32x32x16_bf16(
                          __builtin_bit_cast(bf16x8, au),
                          __builtin_bit_cast(bf16x8, bu), acc, 0, 0, 0);
            }
            int o = nt * 32 + e;
            float b1 = nb1L[o];
#pragma unroll
            for (int q = 0; q < 16; q++) {
                int row = (q & 3) + 8 * (q >> 2) + 4 * half;
                hS[row * HP + o] = bf16_rn(silu_f(acc[q] + b1));
            }
        }
        __syncthreads();

        // ---- GEMM2: h(32x128) @ nw2(128x64) + f residual (waves 0,1) ----
        if (wave < 2) {
            int nt = wave;
            f32x16 acc;
#pragma unroll
            for (int q = 0; q < 16; q++) acc[q] = 0.0f;
#pragma unroll
            for (int ks = 0; ks < 8; ks++) {
                uint4v au = *(const uint4v*)(hS + e * HP + ks * 16 + half * 8);
                uint4v bu = *(const uint4v*)(nw2PL + ((size_t)(nt * 8 + ks) * 512 + lane * 8));
                acc = __builtin_amdgcn_mfma_f32_32x32x16_bf16(
                          __builtin_bit_cast(bf16x8, au),
                          __builtin_bit_cast(bf16x8, bu), acc, 0, 0, 0);
            }
            int o = nt * 32 + e;
            float b2 = nb2L[o];
#pragma unroll
            for (int q = 0; q < 16; q++) {
                int row = (q & 3) + 8 * (q >> 2) + 4 * half;
                float fo = acc[q] + b2 + bf16_up(xS[row * XP + o]);
                fOut[(size_t)(n0 + row) * DIM + o] = fo;
                xS[row * XP + o] = bf16_rn(fo);
            }
        }
        __syncthreads();
    }

    // ---- GEMM3: f'(32x64) @ ew1(64x544) -> a|b rows in outS ----
    {
        uint4v afrag[4];
#pragma unroll
        for (int ks = 0; ks < 4; ks++)
            afrag[ks] = *(const uint4v*)(xS + e * XP + ks * 16 + half * 8);

        for (int nt = wave; nt < NTILE; nt += 4) {
            f32x16 acc;
#pragma unroll
            for (int q = 0; q < 16; q++) acc[q] = 0.0f;
#pragma unroll
            for (int ks = 0; ks < 4; ks++) {
                uint4v bu = *(const uint4v*)(ew1PL + ((size_t)(nt * 4 + ks) * 512 + lane * 8));
                acc = __builtin_amdgcn_mfma_f32_32x32x16_bf16(
                          __builtin_bit_cast(bf16x8, afrag[ks]),
                          __builtin_bit_cast(bf16x8, bu), acc, 0, 0, 0);
            }
            int o = nt * 32 + e;
            float eb = (o < EH) ? eb1L[o] : 0.0f;
            int col = (o < EH) ? o : (o + 14);      // b at 272+(o-EH); o>=516 -> pads
#pragma unroll
            for (int q = 0; q < 16; q++) {
                int row = (q & 3) + 8 * (q >> 2) + 4 * half;
                float v = (o < NOUT) ? (acc[q] + eb) : 0.0f;
                outS[row * OP + col] = bf16_rn(v);
            }
        }
    }
    __syncthreads();

    // ---- coalesced store: per node, a-row (272 sh) then b-row (272 sh) ----
    for (int x = tid; x < 32 * 68; x += 256) {
        int row = x / 68, off = x % 68;
        int gd = gdstS[row];
        uint4v v = *(const uint4v*)(outS + row * OP + off * 8);
        if (off < 34) *(uint4v*)(aH + (size_t)gd * KP + off * 8) = v;
        else          *(uint4v*)(bH + (size_t)gd * KP + (off - 34) * 8) = v;
    }
}

// ---------------------------------------------------------------------------
// MFMA edge kernel (unchanged structure from R4).
// ---------------------------------------------------------------------------
__global__ __launch_bounds__(256, 3)
void k_edge(const unsigned short* __restrict__ aH,
            const unsigned short* __restrict__ bH,
            const float* __restrict__ coorsO,
            const float* __restrict__ wdFL,
            const unsigned short* __restrict__ ew2PL,
            const float* __restrict__ eb2L,
            const unsigned short* __restrict__ cw1PL,
            const float* __restrict__ cb1PL,
            const float* __restrict__ cw2PL,
            const float* __restrict__ cb2L,
            const float* __restrict__ lnbL,
            float* __restrict__ miBuf, float* __restrict__ deltaBuf,
            int Nn, int itpg, int njt) {
    __shared__ unsigned short bS[32 * BPITCH];
    __shared__ float          aSf[8 * APITCH];
    __shared__ float          wdS[KP];
    __shared__ float          cjS[32 * 3];
    __shared__ float          cbS[128], cwS[128];
    __shared__ unsigned short mT[4][32 * 36];

    int bid = blockIdx.x;
    int g   = bid / (itpg * njt);
    int r   = bid % (itpg * njt);
    int it  = r / njt;
    int jt  = r % njt;

    int tid  = threadIdx.x;
    int wave = tid >> 6, lane = tid & 63, half = lane >> 5, e = lane & 31;

    int j0  = jt * 32;
    int njr = Nn - j0; if (njr > 32) njr = 32;
    int i0  = it * 8;
    int nir = Nn - i0; if (nir > 8) nir = 8;

    {
        const unsigned int* src = (const unsigned int*)(bH + (size_t)(g * Nn + j0) * KP);
        unsigned int* dst = (unsigned int*)bS;
        int tot = njr * 136;
        for (int x = tid; x < tot; x += 256) {
            int rr = x / 136, c = x % 136;
            dst[rr * (BPITCH / 2) + c] = src[rr * 136 + c];
        }
        const unsigned short* asrc = aH + (size_t)(g * Nn + i0) * KP;
        int at = nir * KP;
        for (int x = tid; x < at; x += 256) {
            int rr = x / KP, k = x % KP;
            aSf[rr * APITCH + k] = bf16_up(asrc[rr * KP + k]);
        }
        for (int x = tid; x < KP; x += 256) wdS[x] = wdFL[x];
        if (tid < njr * 3) cjS[tid] = coorsO[(g * Nn + j0) * 3 + tid];
        if (tid < 128) { cbS[tid] = cb1PL[tid]; cwS[tid] = cw2PL[tid]; }
    }
    __syncthreads();

    float eb2v = eb2L[e];
    float beta = lnbL[0];
    float cb2v = cb2L[0];

    int  jc     = (e < njr) ? e : (njr - 1);
    bool jvalid = (e < njr);
    float cjx = cjS[jc * 3 + 0], cjy = cjS[jc * 3 + 1], cjz = cjS[jc * 3 + 2];

    unsigned short* mW = &mT[wave][0];
    const unsigned short* bRow = bS + jc * BPITCH;

    for (int s = 0; s < 2; s++) {
        int il = wave * 2 + s;
        if (il >= nir) break;
        int i  = i0 + il;
        int gi = g * Nn + i;

        float cix = coorsO[gi * 3 + 0], ciy = coorsO[gi * 3 + 1], ciz = coorsO[gi * 3 + 2];
        float rx = cix - cjx, ry = ciy - cjy, rz = ciz - cjz;
        float dist = rx * rx + ry * ry + rz * rz;

        const float* aRowF = aSf + il * APITCH;

        f32x16 acc;
#pragma unroll
        for (int q = 0; q < 16; q++) acc[q] = 0.0f;

#pragma unroll
        for (int k0 = 0; k0 < NK0; k0++) {
            int ko = k0 * 16 + half * 8;
            uint2 b01 = *(const uint2*)(bRow + ko);
            uint2 b23 = *(const uint2*)(bRow + ko + 4);
            uint4v eu = *(const uint4v*)(ew2PL + ((size_t)k0 * 64 + lane) * 8);
            unsigned bw[4] = {b01.x, b01.y, b23.x, b23.y};
            uint4v hu;
#pragma unroll
            for (int p = 0; p < 4; p++) {
                float2 av = *(const float2*)(aRowF + ko + 2 * p);
                float2 wv = *(const float2*)(wdS + ko + 2 * p);
                float bL = __uint_as_float(bw[p] << 16);
                float bU = __uint_as_float(bw[p] & 0xFFFF0000u);
                float hL = silu_f(av.x + bL + dist * wv.x);
                float hU = silu_f(av.y + bU + dist * wv.y);
                hu[p] = __builtin_amdgcn_perm(__float_as_uint(hU), __float_as_uint(hL),
                                              0x07060302u);
            }
            acc = __builtin_amdgcn_mfma_f32_32x32x16_bf16(
                      __builtin_bit_cast(bf16x8, hu),
                      __builtin_bit_cast(bf16x8, eu), acc, 0, 0, 0);
        }

        float miAcc = 0.0f;
        float mv[16];
#pragma unroll
        for (int q = 0; q < 16; q++) {
            int row = (q & 3) + 8 * (q >> 2) + 4 * half;
            float m = silu_f(acc[q] + eb2v);
            m = (j0 + row < Nn) ? m : 0.0f;
            mv[q] = m;
            miAcc += m;
        }
#pragma unroll
        for (int q = 0; q < 4; q++) {
            unsigned lo = __builtin_amdgcn_perm(__float_as_uint(mv[q * 4 + 1]),
                                                __float_as_uint(mv[q * 4 + 0]), 0x07060302u);
            unsigned hi = __builtin_amdgcn_perm(__float_as_uint(mv[q * 4 + 3]),
                                                __float_as_uint(mv[q * 4 + 2]), 0x07060302u);
            int row0 = 8 * q + 4 * half;
            *(uint2*)&mW[e * 36 + row0] = make_uint2(lo, hi);
        }

        miAcc += __shfl_xor(miAcc, 32, 64);
        if (half == 0) atomicAdd(&miBuf[gi * MDIM + e], miAcc);

        bf16x8 bq[2];
#pragma unroll
        for (int k0 = 0; k0 < 2; k0++) {
            uint4v t;
#pragma unroll
            for (int p = 0; p < 4; p++) {
                unsigned v0 = mW[(k0 * 16 + half * 8 + 2 * p    ) * 36 + e];
                unsigned v1 = mW[(k0 * 16 + half * 8 + 2 * p + 1) * 36 + e];
                t[p] = v0 | (v1 << 16);
            }
            bq[k0] = __builtin_bit_cast(bf16x8, t);
        }

        float wAcc = 0.0f;
#pragma unroll
        for (int mb = 0; mb < 4; mb++) {
            f32x16 sacc;
#pragma unroll
            for (int q = 0; q < 16; q++) sacc[q] = 0.0f;
#pragma unroll
            for (int k0 = 0; k0 < 2; k0++) {
                uint4v cu = *(const uint4v*)(cw1PL + ((size_t)(mb * 2 + k0) * 64 + lane) * 8);
                sacc = __builtin_amdgcn_mfma_f32_32x32x16_bf16(
                           __builtin_bit_cast(bf16x8, cu), bq[k0], sacc, 0, 0, 0);
            }
            const float* cb1q = cbS + (half * 4 + mb) * 16;
            const float* cw2q = cwS + (half * 4 + mb) * 16;
#pragma unroll
            for (int q = 0; q < 16; q++) {
                wAcc += silu_f(sacc[q] + cb1q[q]) * cw2q[q];
            }
        }
        wAcc += __shfl_xor(wAcc, 32, 64);
        float w = wAcc + cb2v;
        float nrm = sqrtf(dist);
        float scale = (w * 0.02f) * beta * __builtin_amdgcn_rcpf(fmaxf(nrm, 1e-8f));

        float dAx = 0.0f, dAy = 0.0f, dAz = 0.0f;
        if (jvalid && half == 0) {
            dAx = scale * rx; dAy = scale * ry; dAz = scale * rz;
        }
#pragma unroll
        for (int m = 16; m >= 1; m >>= 1) {
            dAx += __shfl_xor(dAx, m, 64);
            dAy += __shfl_xor(dAy, m, 64);
            dAz += __shfl_xor(dAz, m, 64);
        }
        if (lane == 0) {
            atomicAdd(&deltaBuf[gi * 3 + 0], dAx);
            atomicAdd(&deltaBuf[gi * 3 + 1], dAy);
            atomicAdd(&deltaBuf[gi * 3 + 2], dAz);
        }
    }
}

// ---------------------------------------------------------------------------
// Final layer: coords only (features of layer 15 are dead).
// ---------------------------------------------------------------------------
__global__ void k_fin(const float* __restrict__ co, const float* __restrict__ dl,
                      float* __restrict__ out) {
    int idx = blockIdx.x * blockDim.x + threadIdx.x;
    if (idx < NNODE * 3) {
        int gnode = idx / 3, c = idx % 3;
        int nf = inv_map(gnode, 1);   // layer 15 is along-l
        out[nf * 3 + c] = co[idx] + dl[idx];
    }
}

// ---------------------------------------------------------------------------
extern "C" void kernel_launch(void* const* d_in, const int* in_sizes, int n_in,
                              void* d_out, int out_size, void* d_ws, size_t ws_size,
                              hipStream_t stream) {
    (void)in_sizes; (void)n_in; (void)out_size; (void)ws_size;

    const int*   tokens  = (const int*)d_in[0];
    const float* cords   = (const float*)d_in[1];
    const float* tok_emb = (const float*)d_in[2];
    const float* pos_emb = (const float*)d_in[3];
    const float* ew1 = (const float*)d_in[4];
    const float* eb1 = (const float*)d_in[5];
    const float* ew2 = (const float*)d_in[6];
    const float* eb2 = (const float*)d_in[7];
    const float* cw1 = (const float*)d_in[8];
    const float* cb1 = (const float*)d_in[9];
    const float* cw2 = (const float*)d_in[10];
    const float* cb2 = (const float*)d_in[11];
    const float* nw1 = (const float*)d_in[12];
    const float* nb1 = (const float*)d_in[13];
    const float* nw2 = (const float*)d_in[14];
    const float* nb2 = (const float*)d_in[15];
    /* d_in[16] = ln_g : multiplied by zeros in the reference -> unused */
    const float* lnb = (const float*)d_in[17];

    float* wf = (float*)d_ws;
    float* featsA = wf; wf += NNODE * DIM;
    float* featsB = wf; wf += NNODE * DIM;
    float* coorsO0 = wf; wf += NNODE * 3;
    float* coorsO1 = wf; wf += NNODE * 3;
    float* mi0  = wf; wf += NNODE * MDIM;
    float* mi1  = wf; wf += NNODE * MDIM;
    float* dl0  = wf; wf += NNODE * 3;
    float* dl1  = wf; wf += NNODE * 3;
    float* cb1P = wf; wf += NLAY * 128;
    float* cw2P = wf; wf += NLAY * 128;
    float* wdF  = wf; wf += NLAY * KP;

    uintptr_t p = (uintptr_t)wf; p = (p + 15) & ~(uintptr_t)15;
    unsigned short* wh = (unsigned short*)p;
    unsigned short* aHb  = wh; wh += (size_t)NNODE * KP;
    unsigned short* bHb  = wh; wh += (size_t)NNODE * KP;
    unsigned short* ew2P = wh; wh += NLAY * NK0 * 512;
    unsigned short* cw1P = wh; wh += NLAY * 4096;
    unsigned short* ew1P = wh; wh += (size_t)NLAY * NTILE * 4 * 512;
    unsigned short* nw1P = wh; wh += (size_t)NLAY * 4 * 6 * 512;
    unsigned short* nw2P = wh; wh += (size_t)NLAY * 2 * 8 * 512;

    float* coorsO[2] = {coorsO0, coorsO1};
    float* miB[2]    = {mi0, mi1};
    float* dlB[2]    = {dl0, dl1};

    int prepN = NLAY * NTILE * 4 * 512;
    k_prep<<<(prepN + 255) / 256, 256, 0, stream>>>(
        ew1, ew2, cw1, cb1, cw2, nw1, nw2,
        wdF, ew2P, cw1P, cb1P, cw2P, ew1P, nw1P, nw2P);
    k_embed<<<(NNODE * DIM + 255) / 256, 256, 0, stream>>>(
        tokens, tok_emb, pos_emb, featsA);

    float* fCur = featsA; float* fNxt = featsB;

    // pre-only for layer 0 (orientation alongL(0)=0), coors from input
    k_np<<<NNODE / 32, 256, 0, stream>>>(
        fCur, cords, nullptr, nullptr,
        nullptr, nullptr, nullptr, nullptr,
        ew1P + 0, eb1 + 0,
        fNxt, coorsO[0], miB[0], dlB[0],
        aHb, bHb, 0, 0, 0);

    for (int L = 0; L < NLAY; L++) {
        int alongL = (L / 4) % 2;
        int idx  = L & 1;
        int Nn   = alongL ? LL : NN;
        int njt  = alongL ? 3 : 1;
        int itpg = (Nn + 7) / 8;
        int groups = NNODE / Nn;

        k_edge<<<groups * itpg * njt, 256, 0, stream>>>(
            aHb, bHb, coorsO[idx],
            wdF + L * KP, ew2P + (size_t)L * NK0 * 512, eb2 + L * MDIM,
            cw1P + (size_t)L * 4096, cb1P + L * 128, cw2P + L * 128,
            cb2 + L, lnb + L, miB[idx], dlB[idx], Nn, itpg, njt);

        if (L < NLAY - 1) {
            int aL1 = ((L + 1) / 4) % 2;
            int nidx = (L + 1) & 1;
            k_np<<<NNODE / 32, 256, 0, stream>>>(
                fCur, coorsO[idx], miB[idx], dlB[idx],
                nw1P + (size_t)L * 4 * 6 * 512, nb1 + L * NH,
                nw2P + (size_t)L * 2 * 8 * 512, nb2 + L * DIM,
                ew1P + (size_t)(L + 1) * NTILE * 4 * 512, eb1 + (size_t)(L + 1) * EH,
                fNxt, coorsO[nidx], miB[nidx], dlB[nidx],
                aHb, bHb, alongL, aL1, 1);
            float* t = fCur; fCur = fNxt; fNxt = t;
        } else {
            k_fin<<<(NNODE * 3 + 255) / 256, 256, 0, stream>>>(
                coorsO[idx], dlB[idx], (float*)d_out);
        }
    }
}

// Round 6
// 971.991 us; speedup vs baseline: 5.3820x; 1.0854x over previous
//
#include <hip/hip_runtime.h>
#include <math.h>

#define DIM   64
#define MDIM  32
#define NLAY  16
#define PAD   1
#define NB    2
#define LL    96
#define NN    23
#define NNODE (NB*LL*NN)   /* 4416 */
#define EIN   129
#define EH    258          /* EIN*2 */
#define KP    272          /* EH padded to 17*16 */
#define NK0   17
#define NH    128          /* DIM*2 */
#define BPITCH 276         /* bS pitch shorts (8B-aligned rows, 2-way free) */
#define APITCH 276         /* aS pitch floats (16B-aligned rows for b128) */
#define NOUT  516          /* 2*EH outs of the a/b GEMM */
#define NTILE 17           /* ceil(544/32) N-tiles for pre GEMM */
#define XP    104          /* xS pitch shorts */
#define HP    136          /* hS pitch shorts */
#define OP    560          /* outS pitch shorts */

typedef __attribute__((ext_vector_type(8)))  short        bf16x8;
typedef __attribute__((ext_vector_type(16))) float        f32x16;
typedef __attribute__((ext_vector_type(4)))  unsigned int uint4v;
typedef __attribute__((ext_vector_type(2)))  float        f32x2;
typedef __attribute__((ext_vector_type(4)))  float        f32x4;

__device__ __forceinline__ f32x2 mk2(float a, float b) { f32x2 r; r.x = a; r.y = b; return r; }

__device__ __forceinline__ float silu_f(float x) {
    float e = __expf(-x);
    return x * __builtin_amdgcn_rcpf(1.0f + e);
}
// packed silu: 3 pk-VALU + 4 trans per 2 elements
__device__ __forceinline__ f32x2 silu2(f32x2 x) {
    f32x2 t = x * (-1.44269504f);
    f32x2 e;
    e.x = __builtin_amdgcn_exp2f(t.x);
    e.y = __builtin_amdgcn_exp2f(t.y);
    f32x2 den = e + 1.0f;
    f32x2 r;
    r.x = __builtin_amdgcn_rcpf(den.x);
    r.y = __builtin_amdgcn_rcpf(den.y);
    return x * r;
}
__device__ __forceinline__ unsigned short bf16_rn(float x) {
    unsigned u = __float_as_uint(x);
    u += 0x7FFF + ((u >> 16) & 1);
    return (unsigned short)(u >> 16);
}
__device__ __forceinline__ float bf16_up(unsigned short h) {
    return __uint_as_float(((unsigned)h) << 16);
}
__device__ __forceinline__ f32x2 ub2(unsigned bw) {
    return mk2(__uint_as_float(bw << 16), __uint_as_float(bw & 0xFFFF0000u));
}
// H = silu(a + b + dist*wd), packed pair -> bf16x2 word
__device__ __forceinline__ unsigned hpack(f32x2 a2, f32x2 w2, f32x2 b2, f32x2 d2) {
    f32x2 x2 = a2 + b2;
    x2 = __builtin_elementwise_fma(d2, w2, x2);
    f32x2 h2 = silu2(x2);
    return __builtin_amdgcn_perm(__float_as_uint(h2.y), __float_as_uint(h2.x), 0x07060302u);
}
__device__ __forceinline__ int fwd_map(int nf, int alongL) {
    if (alongL) {
        int b = nf / (LL * NN);
        int rem = nf % (LL * NN);
        int l = rem / NN, n = rem % NN;
        return (b * NN + n) * LL + l;
    }
    return nf;
}
__device__ __forceinline__ int inv_map(int gnode, int alongL) {
    if (alongL) {
        int g = gnode / LL, l = gnode % LL;
        int b = g / NN, n = g % NN;
        return (b * LL + l) * NN + n;
    }
    return gnode;
}

// ---------------------------------------------------------------------------
__global__ void k_embed(const int* __restrict__ tokens,
                        const float* __restrict__ tok_emb,
                        const float* __restrict__ pos_emb,
                        float* __restrict__ feats) {
    int idx = blockIdx.x * blockDim.x + threadIdx.x;
    if (idx < NNODE * DIM) {
        int node = idx / DIM, d = idx % DIM;
        int b = node / (LL * NN);
        int rem = node % (LL * NN);
        int n = rem % NN;
        int l = rem / NN;
        int t = tokens[b * LL + l];
        float f = tok_emb[t * DIM + d];
        if (t != PAD) f += pos_emb[(n + 2) * DIM + d];
        feats[idx] = f;
    }
}

// ---------------------------------------------------------------------------
// One-time weight prep into MFMA-fragment layouts (all layers).
// ---------------------------------------------------------------------------
__global__ void k_prep(const float* __restrict__ ew1, const float* __restrict__ ew2,
                       const float* __restrict__ cw1, const float* __restrict__ cb1,
                       const float* __restrict__ cw2,
                       const float* __restrict__ nw1, const float* __restrict__ nw2,
                       float* __restrict__ wdF, unsigned short* __restrict__ ew2P,
                       unsigned short* __restrict__ cw1P,
                       float* __restrict__ cbwP,
                       unsigned short* __restrict__ ew1P,
                       unsigned short* __restrict__ nw1P,
                       unsigned short* __restrict__ nw2P) {
    int idx = blockIdx.x * blockDim.x + threadIdx.x;
    if (idx < NLAY * KP) {
        int L = idx / KP, k = idx % KP;
        float v = (k < EH) ? ew1[(size_t)L * EIN * EH + 128 * EH + k] : 0.0f;
        wdF[idx] = bf16_up(bf16_rn(v));
    }
    if (idx < NLAY * NK0 * 512) {
        int L = idx / (NK0 * 512); int r = idx % (NK0 * 512);
        int k0 = r / 512; int r2 = r % 512;
        int lane = r2 >> 3, j = r2 & 7;
        int k = k0 * 16 + (lane >> 5) * 8 + j;
        int n = lane & 31;
        float v = (k < EH) ? ew2[((size_t)L * EH + k) * MDIM + n] : 0.0f;
        ew2P[idx] = bf16_rn(v);
    }
    if (idx < NLAY * 4096) {
        int L = idx / 4096; int r = idx % 4096;
        int mb = r / 1024; int r2 = r % 1024;
        int k0 = r2 / 512; int r3 = r2 % 512;
        int lane = r3 >> 3, j = r3 & 7;
        int k = k0 * 16 + (lane >> 5) * 8 + j;
        int o = mb * 32 + (lane & 31);
        cw1P[idx] = bf16_rn(cw1[((size_t)L * MDIM + k) * NH + o]);
    }
    if (idx < NLAY * 128) {
        int L = idx / 128; int r = idx % 128;
        int hlf = r / 64; int r2 = r % 64;
        int mb = r2 / 16, reg = r2 % 16;
        int o = mb * 32 + (reg & 3) + 8 * (reg >> 2) + 4 * hlf;
        cbwP[(size_t)L * 256 + r * 2 + 0] = cb1[L * NH + o];
        cbwP[(size_t)L * 256 + r * 2 + 1] = cw2[L * NH + o];
    }
    if (idx < NLAY * NTILE * 4 * 512) {
        int L = idx / (NTILE * 4 * 512); int r = idx % (NTILE * 4 * 512);
        int nt = r / 2048; int r2 = r % 2048;
        int ks = r2 / 512; int r3 = r2 % 512;
        int lane = r3 >> 3, j = r3 & 7;
        int d = ks * 16 + (lane >> 5) * 8 + j;
        int o = nt * 32 + (lane & 31);
        float v = 0.0f;
        if (o < EH)        v = ew1[(size_t)L * EIN * EH + d * EH + o];
        else if (o < NOUT) v = ew1[(size_t)L * EIN * EH + (DIM + d) * EH + (o - EH)];
        ew1P[idx] = bf16_rn(v);
    }
    if (idx < NLAY * 4 * 6 * 512) {
        int L = idx / 12288; int r = idx % 12288;
        int nt = r / 3072; int r2 = r % 3072;
        int ks = r2 / 512; int r3 = r2 % 512;
        int lane = r3 >> 3, j = r3 & 7;
        int k = ks * 16 + (lane >> 5) * 8 + j;
        int n = nt * 32 + (lane & 31);
        nw1P[idx] = bf16_rn(nw1[((size_t)L * (DIM + MDIM) + k) * NH + n]);
    }
    if (idx < NLAY * 2 * 8 * 512) {
        int L = idx / 8192; int r = idx % 8192;
        int nt = r / 4096; int r2 = r % 4096;
        int ks = r2 / 512; int r3 = r2 % 512;
        int lane = r3 >> 3, j = r3 & 7;
        int k = ks * 16 + (lane >> 5) * 8 + j;
        int n = nt * 32 + (lane & 31);
        nw2P[idx] = bf16_rn(nw2[((size_t)L * NH + k) * DIM + n]);
    }
}

// ---------------------------------------------------------------------------
// Fused node-MLP(L) + pre(L+1) (unchanged from R5).
// ---------------------------------------------------------------------------
__global__ __launch_bounds__(256)
void k_np(const float* __restrict__ fIn, const float* __restrict__ coSrc,
          const float* __restrict__ miL, const float* __restrict__ dL,
          const unsigned short* __restrict__ nw1PL, const float* __restrict__ nb1L,
          const unsigned short* __restrict__ nw2PL, const float* __restrict__ nb2L,
          const unsigned short* __restrict__ ew1PL, const float* __restrict__ eb1L,
          float* __restrict__ fOut, float* __restrict__ coDst,
          float* __restrict__ miNext, float* __restrict__ dNext,
          unsigned short* __restrict__ aH, unsigned short* __restrict__ bH,
          int aL0, int aL1, int doNode) {
    __shared__ unsigned short xS[32 * XP];
    __shared__ unsigned short hS[32 * HP];
    __shared__ unsigned short outS[32 * OP];
    __shared__ int gsrcS[32], gdstS[32];

    int n0  = blockIdx.x * 32;
    int tid = threadIdx.x;
    int wave = tid >> 6, lane = tid & 63, half = lane >> 5, e = lane & 31;

    if (tid < 32) {
        gsrcS[tid] = fwd_map(n0 + tid, aL0);
        gdstS[tid] = fwd_map(n0 + tid, aL1);
    }
    __syncthreads();

    for (int i = 0; i < 8; i++) {
        int x = tid + 256 * i;
        int node = x >> 6, d = x & 63;
        xS[node * XP + d] = bf16_rn(fIn[(n0 + node) * DIM + d]);
    }
    if (doNode) {
        for (int i = 0; i < 4; i++) {
            int x = tid + 256 * i;
            int node = x >> 5, d = x & 31;
            xS[node * XP + DIM + d] = bf16_rn(miL[(size_t)gsrcS[node] * MDIM + d]);
        }
    }
    for (int x = tid; x < 32 * 14; x += 256) {
        int node = x / 14, c = EH + x % 14;
        outS[node * OP + c] = 0;
    }
    if (tid < 96) {
        int node = tid / 3, c = tid % 3;
        int gs = gsrcS[node], gd = gdstS[node];
        float cv = coSrc[gs * 3 + c] + (doNode ? dL[gs * 3 + c] : 0.0f);
        coDst[gd * 3 + c] = cv;
        dNext[gd * 3 + c] = 0.0f;
    }
    for (int i = 0; i < 4; i++) {
        int x = tid + 256 * i;
        int node = x >> 5, d = x & 31;
        miNext[(size_t)gdstS[node] * MDIM + d] = 0.0f;
    }
    __syncthreads();

    if (doNode) {
        {
            int nt = wave;
            f32x16 acc;
#pragma unroll
            for (int q = 0; q < 16; q++) acc[q] = 0.0f;
#pragma unroll
            for (int ks = 0; ks < 6; ks++) {
                uint4v au = *(const uint4v*)(xS + e * XP + ks * 16 + half * 8);
                uint4v bu = *(const uint4v*)(nw1PL + ((size_t)(nt * 6 + ks) * 512 + lane * 8));
                acc = __builtin_amdgcn_mfma_f32_32x32x16_bf16(
                          __builtin_bit_cast(bf16x8, au),
                          __builtin_bit_cast(bf16x8, bu), acc, 0, 0, 0);
            }
            int o = nt * 32 + e;
            float b1 = nb1L[o];
#pragma unroll
            for (int q = 0; q < 16; q++) {
                int row = (q & 3) + 8 * (q >> 2) + 4 * half;
                hS[row * HP + o] = bf16_rn(silu_f(acc[q] + b1));
            }
        }
        __syncthreads();

        if (wave < 2) {
            int nt = wave;
            f32x16 acc;
#pragma unroll
            for (int q = 0; q < 16; q++) acc[q] = 0.0f;
#pragma unroll
            for (int ks = 0; ks < 8; ks++) {
                uint4v au = *(const uint4v*)(hS + e * HP + ks * 16 + half * 8);
                uint4v bu = *(const uint4v*)(nw2PL + ((size_t)(nt * 8 + ks) * 512 + lane * 8));
                acc = __builtin_amdgcn_mfma_f32_32x32x16_bf16(
                          __builtin_bit_cast(bf16x8, au),
                          __builtin_bit_cast(bf16x8, bu), acc, 0, 0, 0);
            }
            int o = nt * 32 + e;
            float b2 = nb2L[o];
#pragma unroll
            for (int q = 0; q < 16; q++) {
                int row = (q & 3) + 8 * (q >> 2) + 4 * half;
                float fo = acc[q] + b2 + bf16_up(xS[row * XP + o]);
                fOut[(size_t)(n0 + row) * DIM + o] = fo;
                xS[row * XP + o] = bf16_rn(fo);
            }
        }
        __syncthreads();
    }

    {
        uint4v afrag[4];
#pragma unroll
        for (int ks = 0; ks < 4; ks++)
            afrag[ks] = *(const uint4v*)(xS + e * XP + ks * 16 + half * 8);

        for (int nt = wave; nt < NTILE; nt += 4) {
            f32x16 acc;
#pragma unroll
            for (int q = 0; q < 16; q++) acc[q] = 0.0f;
#pragma unroll
            for (int ks = 0; ks < 4; ks++) {
                uint4v bu = *(const uint4v*)(ew1PL + ((size_t)(nt * 4 + ks) * 512 + lane * 8));
                acc = __builtin_amdgcn_mfma_f32_32x32x16_bf16(
                          __builtin_bit_cast(bf16x8, afrag[ks]),
                          __builtin_bit_cast(bf16x8, bu), acc, 0, 0, 0);
            }
            int o = nt * 32 + e;
            float eb = (o < EH) ? eb1L[o] : 0.0f;
            int col = (o < EH) ? o : (o + 14);
#pragma unroll
            for (int q = 0; q < 16; q++) {
                int row = (q & 3) + 8 * (q >> 2) + 4 * half;
                float v = (o < NOUT) ? (acc[q] + eb) : 0.0f;
                outS[row * OP + col] = bf16_rn(v);
            }
        }
    }
    __syncthreads();

    for (int x = tid; x < 32 * 68; x += 256) {
        int row = x / 68, off = x % 68;
        int gd = gdstS[row];
        uint4v v = *(const uint4v*)(outS + row * OP + off * 8);
        if (off < 34) *(uint4v*)(aH + (size_t)gd * KP + off * 8) = v;
        else          *(uint4v*)(bH + (size_t)gd * KP + (off - 34) * 8) = v;
    }
}

// ---------------------------------------------------------------------------
// MFMA edge kernel v3: packed-fp32 H/silu math, merged 2-i-row K loop,
// b128 LDS loads, interleaved cb/cw.
// ---------------------------------------------------------------------------
__global__ __launch_bounds__(256, 3)
void k_edge(const unsigned short* __restrict__ aH,
            const unsigned short* __restrict__ bH,
            const float* __restrict__ coorsO,
            const float* __restrict__ wdFL,
            const unsigned short* __restrict__ ew2PL,
            const float* __restrict__ eb2L,
            const unsigned short* __restrict__ cw1PL,
            const float* __restrict__ cbwPL,
            const float* __restrict__ cb2L,
            const float* __restrict__ lnbL,
            float* __restrict__ miBuf, float* __restrict__ deltaBuf,
            int Nn, int itpg, int njt) {
    __shared__ unsigned short bS[32 * BPITCH];
    __shared__ __align__(16) float aSf[8 * APITCH];
    __shared__ __align__(16) float wdS[KP];
    __shared__ float cjS[32 * 3];
    __shared__ __align__(16) float cbwS[256];
    __shared__ unsigned short mT[4][32 * 36];

    int bid = blockIdx.x;
    int g   = bid / (itpg * njt);
    int r   = bid % (itpg * njt);
    int it  = r / njt;
    int jt  = r % njt;

    int tid  = threadIdx.x;
    int wave = tid >> 6, lane = tid & 63, half = lane >> 5, e = lane & 31;

    int j0  = jt * 32;
    int njr = Nn - j0; if (njr > 32) njr = 32;
    int i0  = it * 8;
    int nir = Nn - i0; if (nir > 8) nir = 8;

    {
        const unsigned int* src = (const unsigned int*)(bH + (size_t)(g * Nn + j0) * KP);
        unsigned int* dst = (unsigned int*)bS;
        int tot = njr * 136;
        for (int x = tid; x < tot; x += 256) {
            int rr = x / 136, c = x % 136;
            dst[rr * (BPITCH / 2) + c] = src[rr * 136 + c];
        }
        const unsigned short* asrc = aH + (size_t)(g * Nn + i0) * KP;
        int at = nir * KP;
        for (int x = tid; x < at; x += 256) {
            int rr = x / KP, k = x % KP;
            aSf[rr * APITCH + k] = bf16_up(asrc[rr * KP + k]);
        }
        for (int x = tid; x < KP; x += 256) wdS[x] = wdFL[x];
        if (tid < njr * 3) cjS[tid] = coorsO[(g * Nn + j0) * 3 + tid];
        if (tid < 256) cbwS[tid] = cbwPL[tid];
    }
    __syncthreads();

    float eb2v = eb2L[e];
    float beta = lnbL[0];
    float cb2v = cb2L[0];

    int  jc     = (e < njr) ? e : (njr - 1);
    bool jvalid = (e < njr);
    float cjx = cjS[jc * 3 + 0], cjy = cjS[jc * 3 + 1], cjz = cjS[jc * 3 + 2];

    unsigned short* mW = &mT[wave][0];
    const unsigned short* bRow = bS + jc * BPITCH;

    int il0 = wave * 2, il1 = wave * 2 + 1;
    bool v0 = il0 < nir, v1 = il1 < nir;
    int gi0 = g * Nn + i0 + (v0 ? il0 : 0);
    int gi1 = g * Nn + i0 + (v1 ? il1 : 0);

    float rx0, ry0, rz0, d0, rx1, ry1, rz1, d1;
    {
        float cx = coorsO[gi0 * 3 + 0], cy = coorsO[gi0 * 3 + 1], cz = coorsO[gi0 * 3 + 2];
        rx0 = cx - cjx; ry0 = cy - cjy; rz0 = cz - cjz;
        d0 = rx0 * rx0 + ry0 * ry0 + rz0 * rz0;
        cx = coorsO[gi1 * 3 + 0]; cy = coorsO[gi1 * 3 + 1]; cz = coorsO[gi1 * 3 + 2];
        rx1 = cx - cjx; ry1 = cy - cjy; rz1 = cz - cjz;
        d1 = rx1 * rx1 + ry1 * ry1 + rz1 * rz1;
    }
    f32x2 d20 = mk2(d0, d0), d21 = mk2(d1, d1);
    const float* aR0 = aSf + (v0 ? il0 : 0) * APITCH;
    const float* aR1 = aSf + (v1 ? il1 : 0) * APITCH;

    // ---- stage 2: merged K loop for both i-rows ----
    f32x16 acc0, acc1;
#pragma unroll
    for (int q = 0; q < 16; q++) { acc0[q] = 0.0f; acc1[q] = 0.0f; }

#pragma unroll
    for (int k0 = 0; k0 < NK0; k0++) {
        int ko = k0 * 16 + half * 8;
        uint2 bA = *(const uint2*)(bRow + ko);
        uint2 bB = *(const uint2*)(bRow + ko + 4);
        f32x4 wv0 = *(const f32x4*)(wdS + ko);
        f32x4 wv1 = *(const f32x4*)(wdS + ko + 4);
        uint4v eu = *(const uint4v*)(ew2PL + ((size_t)k0 * 64 + lane) * 8);
        f32x2 b2_0 = ub2(bA.x), b2_1 = ub2(bA.y), b2_2 = ub2(bB.x), b2_3 = ub2(bB.y);

        f32x4 a00 = *(const f32x4*)(aR0 + ko);
        f32x4 a01 = *(const f32x4*)(aR0 + ko + 4);
        uint4v hu0;
        hu0[0] = hpack(a00.xy, wv0.xy, b2_0, d20);
        hu0[1] = hpack(a00.zw, wv0.zw, b2_1, d20);
        hu0[2] = hpack(a01.xy, wv1.xy, b2_2, d20);
        hu0[3] = hpack(a01.zw, wv1.zw, b2_3, d20);
        acc0 = __builtin_amdgcn_mfma_f32_32x32x16_bf16(
                   __builtin_bit_cast(bf16x8, hu0),
                   __builtin_bit_cast(bf16x8, eu), acc0, 0, 0, 0);

        f32x4 a10 = *(const f32x4*)(aR1 + ko);
        f32x4 a11 = *(const f32x4*)(aR1 + ko + 4);
        uint4v hu1;
        hu1[0] = hpack(a10.xy, wv0.xy, b2_0, d21);
        hu1[1] = hpack(a10.zw, wv0.zw, b2_1, d21);
        hu1[2] = hpack(a11.xy, wv1.xy, b2_2, d21);
        hu1[3] = hpack(a11.zw, wv1.zw, b2_3, d21);
        acc1 = __builtin_amdgcn_mfma_f32_32x32x16_bf16(
                   __builtin_bit_cast(bf16x8, hu1),
                   __builtin_bit_cast(bf16x8, eu), acc1, 0, 0, 0);
    }

    f32x2 ebp = mk2(eb2v, eb2v);

#pragma unroll
    for (int s = 0; s < 2; s++) {
        if (!(s ? v1 : v0)) continue;
        int gi = s ? gi1 : gi0;
        float rx = s ? rx1 : rx0, ry = s ? ry1 : ry0, rz = s ? rz1 : rz0;
        float dist = s ? d1 : d0;

        // ---- stage 2 epilogue ----
        float mv[16];
        f32x2 mi2 = mk2(0.0f, 0.0f);
        if (njr == 32) {
#pragma unroll
            for (int qp = 0; qp < 8; qp++) {
                int q = qp * 2;
                f32x2 x2 = mk2(s ? acc1[q] : acc0[q], s ? acc1[q + 1] : acc0[q + 1]) + ebp;
                f32x2 m2 = silu2(x2);
                mv[q] = m2.x; mv[q + 1] = m2.y;
                mi2 += m2;
            }
        } else {
#pragma unroll
            for (int qp = 0; qp < 8; qp++) {
                int q = qp * 2;
                f32x2 x2 = mk2(s ? acc1[q] : acc0[q], s ? acc1[q + 1] : acc0[q + 1]) + ebp;
                f32x2 m2 = silu2(x2);
                int row0 = (q & 3) + 8 * (q >> 2) + 4 * half;
                if (j0 + row0 >= Nn) m2.x = 0.0f;
                if (j0 + row0 + 1 >= Nn) m2.y = 0.0f;
                mv[q] = m2.x; mv[q + 1] = m2.y;
                mi2 += m2;
            }
        }
        float miAcc = mi2.x + mi2.y;

#pragma unroll
        for (int q = 0; q < 4; q++) {
            unsigned lo = __builtin_amdgcn_perm(__float_as_uint(mv[q * 4 + 1]),
                                                __float_as_uint(mv[q * 4 + 0]), 0x07060302u);
            unsigned hi = __builtin_amdgcn_perm(__float_as_uint(mv[q * 4 + 3]),
                                                __float_as_uint(mv[q * 4 + 2]), 0x07060302u);
            int row0 = 8 * q + 4 * half;
            *(uint2*)&mW[e * 36 + row0] = make_uint2(lo, hi);
        }

        miAcc += __shfl_xor(miAcc, 32, 64);
        if (half == 0) atomicAdd(&miBuf[gi * MDIM + e], miAcc);

        // ---- stage 3 ----
        bf16x8 bq[2];
#pragma unroll
        for (int k0 = 0; k0 < 2; k0++) {
            uint4v t;
#pragma unroll
            for (int p = 0; p < 4; p++) {
                unsigned w0 = mW[(k0 * 16 + half * 8 + 2 * p    ) * 36 + e];
                unsigned w1 = mW[(k0 * 16 + half * 8 + 2 * p + 1) * 36 + e];
                t[p] = w0 | (w1 << 16);
            }
            bq[k0] = __builtin_bit_cast(bf16x8, t);
        }

        f32x2 w2a = mk2(0.0f, 0.0f);
#pragma unroll
        for (int mb = 0; mb < 4; mb++) {
            f32x16 sacc;
#pragma unroll
            for (int q = 0; q < 16; q++) sacc[q] = 0.0f;
#pragma unroll
            for (int k0 = 0; k0 < 2; k0++) {
                uint4v cu = *(const uint4v*)(cw1PL + ((size_t)(mb * 2 + k0) * 64 + lane) * 8);
                sacc = __builtin_amdgcn_mfma_f32_32x32x16_bf16(
                           __builtin_bit_cast(bf16x8, cu), bq[k0], sacc, 0, 0, 0);
            }
            const f32x4* cv = (const f32x4*)(cbwS + (half * 4 + mb) * 32);
#pragma unroll
            for (int qp = 0; qp < 8; qp++) {
                f32x4 c4 = cv[qp];
                f32x2 s2 = mk2(sacc[2 * qp], sacc[2 * qp + 1]) + mk2(c4.x, c4.z);
                f32x2 p2 = silu2(s2);
                w2a = __builtin_elementwise_fma(p2, mk2(c4.y, c4.w), w2a);
            }
        }
        float wAcc = w2a.x + w2a.y;
        wAcc += __shfl_xor(wAcc, 32, 64);
        float w = wAcc + cb2v;
        float nrm = sqrtf(dist);
        float scale = (w * 0.02f) * beta * __builtin_amdgcn_rcpf(fmaxf(nrm, 1e-8f));

        float dAx = 0.0f, dAy = 0.0f, dAz = 0.0f;
        if (jvalid && half == 0) {
            dAx = scale * rx; dAy = scale * ry; dAz = scale * rz;
        }
#pragma unroll
        for (int m = 16; m >= 1; m >>= 1) {
            dAx += __shfl_xor(dAx, m, 64);
            dAy += __shfl_xor(dAy, m, 64);
            dAz += __shfl_xor(dAz, m, 64);
        }
        if (lane == 0) {
            atomicAdd(&deltaBuf[gi * 3 + 0], dAx);
            atomicAdd(&deltaBuf[gi * 3 + 1], dAy);
            atomicAdd(&deltaBuf[gi * 3 + 2], dAz);
        }
    }
}

// ---------------------------------------------------------------------------
__global__ void k_fin(const float* __restrict__ co, const float* __restrict__ dl,
                      float* __restrict__ out) {
    int idx = blockIdx.x * blockDim.x + threadIdx.x;
    if (idx < NNODE * 3) {
        int gnode = idx / 3, c = idx % 3;
        int nf = inv_map(gnode, 1);   // layer 15 is along-l
        out[nf * 3 + c] = co[idx] + dl[idx];
    }
}

// ---------------------------------------------------------------------------
extern "C" void kernel_launch(void* const* d_in, const int* in_sizes, int n_in,
                              void* d_out, int out_size, void* d_ws, size_t ws_size,
                              hipStream_t stream) {
    (void)in_sizes; (void)n_in; (void)out_size; (void)ws_size;

    const int*   tokens  = (const int*)d_in[0];
    const float* cords   = (const float*)d_in[1];
    const float* tok_emb = (const float*)d_in[2];
    const float* pos_emb = (const float*)d_in[3];
    const float* ew1 = (const float*)d_in[4];
    const float* eb1 = (const float*)d_in[5];
    const float* ew2 = (const float*)d_in[6];
    const float* eb2 = (const float*)d_in[7];
    const float* cw1 = (const float*)d_in[8];
    const float* cb1 = (const float*)d_in[9];
    const float* cw2 = (const float*)d_in[10];
    const float* cb2 = (const float*)d_in[11];
    const float* nw1 = (const float*)d_in[12];
    const float* nb1 = (const float*)d_in[13];
    const float* nw2 = (const float*)d_in[14];
    const float* nb2 = (const float*)d_in[15];
    /* d_in[16] = ln_g : multiplied by zeros in the reference -> unused */
    const float* lnb = (const float*)d_in[17];

    float* wf = (float*)d_ws;
    float* featsA = wf; wf += NNODE * DIM;
    float* featsB = wf; wf += NNODE * DIM;
    float* coorsO0 = wf; wf += NNODE * 3;
    float* coorsO1 = wf; wf += NNODE * 3;
    float* mi0  = wf; wf += NNODE * MDIM;
    float* mi1  = wf; wf += NNODE * MDIM;
    float* dl0  = wf; wf += NNODE * 3;
    float* dl1  = wf; wf += NNODE * 3;
    float* cbwP = wf; wf += NLAY * 256;
    float* wdF  = wf; wf += NLAY * KP;

    uintptr_t p = (uintptr_t)wf; p = (p + 15) & ~(uintptr_t)15;
    unsigned short* wh = (unsigned short*)p;
    unsigned short* aHb  = wh; wh += (size_t)NNODE * KP;
    unsigned short* bHb  = wh; wh += (size_t)NNODE * KP;
    unsigned short* ew2P = wh; wh += NLAY * NK0 * 512;
    unsigned short* cw1P = wh; wh += NLAY * 4096;
    unsigned short* ew1P = wh; wh += (size_t)NLAY * NTILE * 4 * 512;
    unsigned short* nw1P = wh; wh += (size_t)NLAY * 4 * 6 * 512;
    unsigned short* nw2P = wh; wh += (size_t)NLAY * 2 * 8 * 512;

    float* coorsO[2] = {coorsO0, coorsO1};
    float* miB[2]    = {mi0, mi1};
    float* dlB[2]    = {dl0, dl1};

    int prepN = NLAY * NTILE * 4 * 512;
    k_prep<<<(prepN + 255) / 256, 256, 0, stream>>>(
        ew1, ew2, cw1, cb1, cw2, nw1, nw2,
        wdF, ew2P, cw1P, cbwP, ew1P, nw1P, nw2P);
    k_embed<<<(NNODE * DIM + 255) / 256, 256, 0, stream>>>(
        tokens, tok_emb, pos_emb, featsA);

    float* fCur = featsA; float* fNxt = featsB;

    k_np<<<NNODE / 32, 256, 0, stream>>>(
        fCur, cords, nullptr, nullptr,
        nullptr, nullptr, nullptr, nullptr,
        ew1P + 0, eb1 + 0,
        fNxt, coorsO[0], miB[0], dlB[0],
        aHb, bHb, 0, 0, 0);

    for (int L = 0; L < NLAY; L++) {
        int alongL = (L / 4) % 2;
        int idx  = L & 1;
        int Nn   = alongL ? LL : NN;
        int njt  = alongL ? 3 : 1;
        int itpg = (Nn + 7) / 8;
        int groups = NNODE / Nn;

        k_edge<<<groups * itpg * njt, 256, 0, stream>>>(
            aHb, bHb, coorsO[idx],
            wdF + L * KP, ew2P + (size_t)L * NK0 * 512, eb2 + L * MDIM,
            cw1P + (size_t)L * 4096, cbwP + (size_t)L * 256,
            cb2 + L, lnb + L, miB[idx], dlB[idx], Nn, itpg, njt);

        if (L < NLAY - 1) {
            int aL1 = ((L + 1) / 4) % 2;
            int nidx = (L + 1) & 1;
            k_np<<<NNODE / 32, 256, 0, stream>>>(
                fCur, coorsO[idx], miB[idx], dlB[idx],
                nw1P + (size_t)L * 4 * 6 * 512, nb1 + L * NH,
                nw2P + (size_t)L * 2 * 8 * 512, nb2 + L * DIM,
                ew1P + (size_t)(L + 1) * NTILE * 4 * 512, eb1 + (size_t)(L + 1) * EH,
                fNxt, coorsO[nidx], miB[nidx], dlB[nidx],
                aHb, bHb, alongL, aL1, 1);
            float* t = fCur; fCur = fNxt; fNxt = t;
        } else {
            k_fin<<<(NNODE * 3 + 255) / 256, 256, 0, stream>>>(
                coorsO[idx], dlB[idx], (float*)d_out);
        }
    }
}